// Round 6
// baseline (1018.991 us; speedup 1.0000x reference)
//
#include <hip/hip_runtime.h>
#include <math.h>

// ---- fixed problem dims ----
constexpr int Bb  = 16;
constexpr int Tt  = 16;
constexpr int Nn  = 196;   // patches (14x14)
constexpr int Cc  = 768;
constexpr int Aa  = 192;
constexpr int KK  = 8;     // TOPK
constexpr int NCAND = 16;  // fp32 candidates refined in f64
constexpr int BT  = Bb * Tt;            // 256
constexpr int BTN = BT * Nn;            // 50176
constexpr int BKT = Bb * KK * Tt;       // 2048 anchor-token rows
constexpr size_t SZ = (size_t)BTN * Aa; // 9,633,792 floats

typedef unsigned short ushortt;
typedef __attribute__((ext_vector_type(8))) short bf16x8;
typedef __attribute__((ext_vector_type(4))) float f32x4;
typedef __attribute__((ext_vector_type(4))) unsigned short u16x4;
typedef __attribute__((ext_vector_type(8))) unsigned short u16x8;

static __device__ __forceinline__ float gelu_f(float x) {
  return 0.5f * x * (1.0f + erff(x * 0.7071067811865476f));
}
static __device__ __forceinline__ ushortt f2bf(float f) {
  unsigned u = __float_as_uint(f);
  u += 0x7FFFu + ((u >> 16) & 1u);  // round-to-nearest-even
  return (ushortt)(u >> 16);
}
static __device__ __forceinline__ float bf2f(ushortt u) {
  return __uint_as_float(((unsigned)u) << 16);
}

// ============================================================
// bf16 MFMA GEMM: C[m,n] = sum_k A[m,k]*W[n,k] (+bias)(+epilogue)
// AT: float (staged->bf16) or ushort (bf16). CT: float or ushort.
// BM=128 BN=96 BK=32, 256 thr = 4 waves (2x2), wave tile 64x48
// (12 MFMA/step). EPI: 0 plain, 1 gelu, 2 mapped residual fp32.
// Grid (Nc/96, M/128); col-fastest + bijective XCD swizzle (nwg%8==0).
// ============================================================
template <typename AT, typename CT, int ROWMAP, int BIAS, int EPI>
__global__ __launch_bounds__(256) void gemm_mfma(
    const AT* __restrict__ Ain, const float* __restrict__ W,
    const float* __restrict__ bias, CT* __restrict__ Cout,
    const float* __restrict__ resid, int M, int Nc, int K) {
  constexpr int PIT = 40;  // bf16 pitch (32+8 pad) -> worst 2-way (free)
  __shared__ ushortt As[2][128 * PIT];
  __shared__ ushortt Bs[2][96 * PIT];
  const int tid = threadIdx.x;

  const int ncb = gridDim.x;
  const int nwg = ncb * gridDim.y;
  const int bid = blockIdx.y * ncb + blockIdx.x;
  const int cpx = nwg >> 3;
  const int swz = (bid & 7) * cpx + (bid >> 3);
  const int row0 = (swz / ncb) * 128;
  const int col0 = (swz % ncb) * 96;

  const int wid = tid >> 6;
  const int lane = tid & 63;
  const int wr = wid >> 1;       // 0..1 -> +64 rows
  const int wc = wid & 1;        // 0..1 -> +48 cols
  const int l15 = lane & 15;
  const int kgrp = lane >> 4;    // 0..3

  const int nsteps = K >> 5;

  const float* arowf[4];
  const ushortt* arowb[2];
  if constexpr (sizeof(AT) == 4) {
    const int srow = tid >> 3;
#pragma unroll
    for (int p = 0; p < 4; ++p) {
      int r = row0 + srow + 32 * p;
      if (ROWMAP) {
        int bt = r / Nn;
        int n = r - bt * Nn;
        arowf[p] = (const float*)Ain + (size_t)(bt * (Nn + 1) + 1 + n) * K;
      } else {
        arowf[p] = (const float*)Ain + (size_t)r * K;
      }
    }
  } else {
    const int srow2 = tid >> 2;
#pragma unroll
    for (int p = 0; p < 2; ++p)
      arowb[p] = (const ushortt*)Ain + (size_t)(row0 + srow2 + 64 * p) * K;
  }
  const float* browp[3];
  {
    const int srow = tid >> 3;
#pragma unroll
    for (int p = 0; p < 3; ++p)
      browp[p] = W + (size_t)(col0 + srow + 32 * p) * K;
  }

  f32x4 acc[4][3];
#pragma unroll
  for (int i = 0; i < 4; ++i)
#pragma unroll
    for (int j = 0; j < 3; ++j) acc[i][j] = (f32x4){0.f, 0.f, 0.f, 0.f};

  float4 apre[4], bpre[3];
  u16x8 apreb[2];

#define STAGE_LOAD(k0)                                                       \
  if constexpr (sizeof(AT) == 4) {                                           \
    const int quad = tid & 7;                                                \
    _Pragma("unroll") for (int p = 0; p < 4; ++p)                            \
        apre[p] = *(const float4*)(arowf[p] + (k0) + quad * 4);              \
  } else {                                                                   \
    const int quad2 = tid & 3;                                               \
    _Pragma("unroll") for (int p = 0; p < 2; ++p)                            \
        apreb[p] = *(const u16x8*)(arowb[p] + (k0) + quad2 * 8);             \
  }                                                                          \
  {                                                                          \
    const int quad = tid & 7;                                                \
    _Pragma("unroll") for (int p = 0; p < 3; ++p)                            \
        bpre[p] = *(const float4*)(browp[p] + (k0) + quad * 4);              \
  }

#define STAGE_WRITE(buf)                                                     \
  if constexpr (sizeof(AT) == 4) {                                           \
    const int quad = tid & 7, srow = tid >> 3;                               \
    _Pragma("unroll") for (int p = 0; p < 4; ++p) {                          \
      u16x4 b = {f2bf(apre[p].x), f2bf(apre[p].y), f2bf(apre[p].z),          \
                 f2bf(apre[p].w)};                                           \
      *(u16x4*)&As[buf][(srow + 32 * p) * PIT + quad * 4] = b;               \
    }                                                                        \
  } else {                                                                   \
    const int quad2 = tid & 3, srow2 = tid >> 2;                             \
    _Pragma("unroll") for (int p = 0; p < 2; ++p)                            \
        *(u16x8*)&As[buf][(srow2 + 64 * p) * PIT + quad2 * 8] = apreb[p];    \
  }                                                                          \
  {                                                                          \
    const int quad = tid & 7, srow = tid >> 3;                               \
    _Pragma("unroll") for (int p = 0; p < 3; ++p) {                          \
      u16x4 b = {f2bf(bpre[p].x), f2bf(bpre[p].y), f2bf(bpre[p].z),          \
                 f2bf(bpre[p].w)};                                           \
      *(u16x4*)&Bs[buf][(srow + 32 * p) * PIT + quad * 4] = b;               \
    }                                                                        \
  }

  STAGE_LOAD(0);
  STAGE_WRITE(0);
  __syncthreads();

  int cur = 0;
  for (int step = 0; step < nsteps; ++step) {
    const bool pref = (step + 1 < nsteps);
    if (pref) {
      int k0 = (step + 1) << 5;
      STAGE_LOAD(k0);
    }
    bf16x8 af[4], bfv[3];
#pragma unroll
    for (int fm = 0; fm < 4; ++fm)
      af[fm] = *(const bf16x8*)&As[cur][(wr * 64 + fm * 16 + l15) * PIT + kgrp * 8];
#pragma unroll
    for (int fn = 0; fn < 3; ++fn)
      bfv[fn] = *(const bf16x8*)&Bs[cur][(wc * 48 + fn * 16 + l15) * PIT + kgrp * 8];
#pragma unroll
    for (int fm = 0; fm < 4; ++fm)
#pragma unroll
      for (int fn = 0; fn < 3; ++fn)
        acc[fm][fn] = __builtin_amdgcn_mfma_f32_16x16x32_bf16(
            af[fm], bfv[fn], acc[fm][fn], 0, 0, 0);
    if (pref) {
      STAGE_WRITE(cur ^ 1);
    }
    __syncthreads();
    cur ^= 1;
  }
#undef STAGE_LOAD
#undef STAGE_WRITE

  // epilogue: C/D layout col=lane&15, row=(lane>>4)*4+j
#pragma unroll
  for (int fm = 0; fm < 4; ++fm) {
    int rbase = row0 + wr * 64 + fm * 16 + kgrp * 4;
#pragma unroll
    for (int fn = 0; fn < 3; ++fn) {
      int c = col0 + wc * 48 + fn * 16 + l15;
      float bv = BIAS ? bias[c] : 0.f;
#pragma unroll
      for (int j = 0; j < 4; ++j) {
        int r = rbase + j;
        float v = acc[fm][fn][j] + bv;
        if (EPI == 1) v = gelu_f(v);
        if (EPI == 2) {
          int bt = r / Nn;
          int n = r - bt * Nn;
          size_t off = (size_t)(bt * (Nn + 1) + 1 + n) * Nc + c;
          ((float*)Cout)[off] = resid[off] + v;
        } else {
          if constexpr (sizeof(CT) == 4)
            Cout[(size_t)r * Nc + c] = (CT)v;
          else
            ((ushortt*)Cout)[(size_t)r * Nc + c] = f2bf(v);
        }
      }
    }
  }
}

// ============================================================
// delta (bf16) + per-(b,t) |delta| partials
// ============================================================
__global__ void delta_kernel(const ushortt* __restrict__ ph,
                             ushortt* __restrict__ delta,
                             float* __restrict__ dppart) {
  int bt = blockIdx.x;
  int t = bt & 15;
  int a = threadIdx.x;
  const ushortt* cur = ph + (size_t)bt * Nn * Aa + a;
  ushortt* dl = delta + (size_t)bt * Nn * Aa + a;
  float acc = 0.f;
  if (t == 0) {
    for (int n = 0; n < Nn; ++n) dl[(size_t)n * Aa] = 0;
  } else {
    const ushortt* prev = cur - (size_t)Nn * Aa;
    for (int n = 0; n < Nn; ++n) {
      float d = bf2f(cur[(size_t)n * Aa]) - bf2f(prev[(size_t)n * Aa]);
      dl[(size_t)n * Aa] = f2bf(d);
      acc += fabsf(d);
    }
  }
  dppart[bt * Aa + a] = acc;
}

// sal[row] = mean_a |delta[row,a]| (fp32, candidate stage only)
__global__ void sal_kernel(const ushortt* __restrict__ delta,
                           float* __restrict__ sal) {
  int row = blockIdx.x * 4 + (threadIdx.x >> 6);
  int lane = threadIdx.x & 63;
  const ushortt* d = delta + (size_t)row * Aa;
  float s = fabsf(bf2f(d[lane])) + fabsf(bf2f(d[lane + 64])) +
            fabsf(bf2f(d[lane + 128]));
#pragma unroll
  for (int off = 32; off > 0; off >>= 1) s += __shfl_xor(s, off, 64);
  if (lane == 0) sal[row] = s * (1.0f / 192.0f);
}

// ============================================================
// top-16 fp32 candidates per (b,t); descending val, ties -> smaller n
// ============================================================
__global__ void topcand_kernel(const float* __restrict__ sal,
                               int* __restrict__ cand) {
  int bt = blockIdx.x;
  int lane = threadIdx.x;
  unsigned long long key[4];
#pragma unroll
  for (int j = 0; j < 4; ++j) {
    int n = lane + 64 * j;
    if (n < Nn) {
      unsigned fb = __float_as_uint(sal[(size_t)bt * Nn + n]);
      key[j] = ((unsigned long long)fb << 32) |
               (unsigned long long)(0xFFFFFFFFu - (unsigned)n);
    } else {
      key[j] = 0ULL;
    }
  }
  for (int r = 0; r < NCAND; ++r) {
    unsigned long long m = key[0];
    if (key[1] > m) m = key[1];
    if (key[2] > m) m = key[2];
    if (key[3] > m) m = key[3];
#pragma unroll
    for (int off = 32; off > 0; off >>= 1) {
      unsigned long long o = __shfl_xor(m, off, 64);
      if (o > m) m = o;
    }
    if (lane == 0)
      cand[bt * NCAND + r] = (int)(0xFFFFFFFFu - (unsigned)(m & 0xFFFFFFFFull));
#pragma unroll
    for (int j = 0; j < 4; ++j)
      if (key[j] == m) key[j] = 0ULL;
  }
}

// ============================================================
// f64 refine, one candidate per block (grid BT x NCAND, 192 thr).
// sal64 = mean_a |sum_c (x_t - x_{t-1})[n,c] * down_w[a,c]|
// diff computed on the fly (wave-broadcast L2 reads), no big LDS.
// ============================================================
__global__ __launch_bounds__(192) void refine_kernel(
    const float* __restrict__ x, const float* __restrict__ down_w,
    const int* __restrict__ cand, double* __restrict__ sal64) {
  int bt = blockIdx.x;
  int ci = blockIdx.y;
  int t = bt & 15;
  int tid = threadIdx.x;
  if (t == 0) {
    if (tid == 0) sal64[bt * NCAND + ci] = 0.0;
    return;
  }
  int n = cand[bt * NCAND + ci];
  const float* rt = x + ((size_t)bt * (Nn + 1) + 1 + n) * Cc;
  const float* rp = rt - (size_t)(Nn + 1) * Cc;
  const float* wrow = down_w + (size_t)tid * Cc;
  double acc = 0.0;
  for (int c = 0; c < Cc; c += 4) {
    float4 w4 = *(const float4*)(wrow + c);
    float4 a4 = *(const float4*)(rt + c);
    float4 b4 = *(const float4*)(rp + c);
    acc += (double)w4.x * ((double)a4.x - (double)b4.x) +
           (double)w4.y * ((double)a4.y - (double)b4.y) +
           (double)w4.z * ((double)a4.z - (double)b4.z) +
           (double)w4.w * ((double)a4.w - (double)b4.w);
  }
  double v = fabs(acc);
#pragma unroll
  for (int off = 32; off > 0; off >>= 1) v += __shfl_xor(v, off, 64);
  __shared__ double part[3];
  int wv = tid >> 6, ln = tid & 63;
  if (ln == 0) part[wv] = v;
  __syncthreads();
  if (tid == 0)
    sal64[bt * NCAND + ci] = (part[0] + part[1] + part[2]) * (1.0 / 192.0);
}

// final top-8 by (sal64 desc, n asc)
__global__ void select_kernel(const double* __restrict__ sal64,
                              const int* __restrict__ cand,
                              int* __restrict__ idx) {
  int bt = blockIdx.x;
  int t = bt & 15;
  if (threadIdx.x != 0) return;
  if (t == 0) {
    for (int r = 0; r < KK; ++r) idx[bt * KK + r] = r;
    return;
  }
  double v[NCAND];
  int nn[NCAND];
  bool used[NCAND];
  for (int i = 0; i < NCAND; ++i) {
    v[i] = sal64[bt * NCAND + i];
    nn[i] = cand[bt * NCAND + i];
    used[i] = false;
  }
  for (int r = 0; r < KK; ++r) {
    int best = -1;
    for (int i = 0; i < NCAND; ++i) {
      if (used[i]) continue;
      if (best < 0 || v[i] > v[best] ||
          (v[i] == v[best] && nn[i] < nn[best]))
        best = i;
    }
    used[best] = true;
    idx[bt * KK + r] = nn[best];
  }
}

// ============================================================
// anchor attention: gather(bf16) -> GEMM qkv -> core -> GEMMs
// ============================================================
__global__ void gather_kernel(const ushortt* __restrict__ ph,
                              const ushortt* __restrict__ delta,
                              const int* __restrict__ idx,
                              ushortt* __restrict__ tok) {
  int row = blockIdx.x;  // (b*KK+k)*16+t
  int t = row & 15;
  int bk = row >> 4;
  int b = bk >> 3, k = bk & 7;
  int a = threadIdx.x;
  int n = idx[(b * 16 + t) * KK + k];
  size_t off = ((size_t)(b * 16 + t) * Nn + n) * Aa + a;
  tok[(size_t)row * Aa + a] = f2bf(bf2f(ph[off]) + bf2f(delta[off]));
}

__global__ __launch_bounds__(256) void attn_core(
    const float* __restrict__ qkv, float* __restrict__ o) {
  constexpr int P = 580;
  __shared__ float sq[16 * P];
  __shared__ float ssc[4][16][17];
  int bk = blockIdx.x;
  int tid = threadIdx.x;
  const float* src = qkv + (size_t)bk * 16 * 576;
  for (int e = tid; e < 16 * 144; e += 256) {
    int r = e / 144, c4 = e % 144;
    float4 v = *(const float4*)(src + r * 576 + c4 * 4);
    *(float4*)(&sq[r * P + c4 * 4]) = v;
  }
  __syncthreads();
  int h = tid >> 6, lane = tid & 63;
#pragma unroll
  for (int s4 = 0; s4 < 4; ++s4) {
    int e = lane + 64 * s4;
    int i = e >> 4, j = e & 15;
    const float* q = sq + i * P + h * 48;
    const float* k2 = sq + j * P + 192 + h * 48;
    float s = 0.f;
#pragma unroll
    for (int d = 0; d < 48; ++d) s = fmaf(q[d], k2[d], s);
    ssc[h][i][j] = s * 0.14433756729740643f;  // 1/sqrt(48)
  }
  __syncthreads();
  if (lane < 16) {
    float* r = ssc[h][lane];
    float mx = r[0];
    for (int j = 1; j < 16; ++j) mx = fmaxf(mx, r[j]);
    float sum = 0.f;
    for (int j = 0; j < 16; ++j) {
      float ev = expf(r[j] - mx);
      r[j] = ev;
      sum += ev;
    }
    float inv = 1.0f / sum;
    for (int j = 0; j < 16; ++j) r[j] *= inv;
  }
  __syncthreads();
#pragma unroll
  for (int s4 = 0; s4 < 12; ++s4) {
    int e = lane + 64 * s4;
    int i = e / 48, d = e - i * 48;
    float s = 0.f;
#pragma unroll
    for (int j = 0; j < 16; ++j)
      s = fmaf(ssc[h][i][j], sq[j * P + 384 + h * 48 + d], s);
    o[((size_t)bk * 16 + i) * 192 + h * 48 + d] = s;
  }
}

__global__ void appart_kernel(const float* __restrict__ attout,
                              float* __restrict__ appart) {
  int bk = blockIdx.x;
  int a = threadIdx.x;
  float s = 0.f;
  for (int t = 0; t < Tt; ++t)
    s += attout[((size_t)bk * Tt + t) * Aa + a];
  appart[bk * Aa + a] = s;
}

// depthwise 3x3 SAME conv over 14x14 + gelu; bf16 in/out
__global__ void conv2d_kernel(const ushortt* __restrict__ ph,
                              const float* __restrict__ ldw,
                              ushortt* __restrict__ og) {
  size_t e = (size_t)blockIdx.x * 256 + threadIdx.x;
  int a = (int)(e % Aa);
  size_t r = e / Aa;
  int n = (int)(r % Nn);
  int bt = (int)(r / Nn);
  int y = n / 14, x = n % 14;
  const ushortt* base = ph + (size_t)bt * Nn * Aa + a;
  const float* w = ldw + a * 9;
  float s = 0.f;
#pragma unroll
  for (int dy = -1; dy <= 1; ++dy) {
    int yy = y + dy;
    if (yy < 0 || yy >= 14) continue;
#pragma unroll
    for (int dx = -1; dx <= 1; ++dx) {
      int xc = x + dx;
      if (xc < 0 || xc >= 14) continue;
      s = fmaf(bf2f(base[(size_t)(yy * 14 + xc) * Aa]),
               w[(dy + 1) * 3 + (dx + 1)], s);
    }
  }
  og[e] = f2bf(gelu_f(s));
}

// depthwise k=3 SAME conv over t + gelu; bf16 in/out
__global__ void conv1d_kernel(const ushortt* __restrict__ delta,
                              const float* __restrict__ tdw,
                              ushortt* __restrict__ og) {
  size_t e = (size_t)blockIdx.x * 256 + threadIdx.x;
  int a = (int)(e % Aa);
  size_t r = e / Aa;
  int n = (int)(r % Nn);
  int bt = (int)(r / Nn);
  int t = bt & 15, b = bt >> 4;
  const float* w = tdw + a * 3;
  float s = 0.f;
#pragma unroll
  for (int j = 0; j < 3; ++j) {
    int tt = t + j - 1;
    if (tt >= 0 && tt < Tt)
      s = fmaf(bf2f(delta[((size_t)(b * Tt + tt) * Nn + n) * Aa + a]), w[j], s);
  }
  og[e] = f2bf(gelu_f(s));
}

// in-place LayerNorm over last dim (192); one wave per row (bf16)
__global__ void ln_kernel(ushortt* __restrict__ buf,
                          const float* __restrict__ g,
                          const float* __restrict__ bb) {
  size_t row = (size_t)blockIdx.x * 4 + (threadIdx.x >> 6);
  int lane = threadIdx.x & 63;
  ushortt* p = buf + row * Aa;
  float v0 = bf2f(p[lane]), v1 = bf2f(p[lane + 64]), v2 = bf2f(p[lane + 128]);
  float s = v0 + v1 + v2;
#pragma unroll
  for (int off = 32; off > 0; off >>= 1) s += __shfl_xor(s, off, 64);
  float m = s * (1.0f / 192.0f);
  float d0 = v0 - m, d1 = v1 - m, d2 = v2 - m;
  float ss = d0 * d0 + d1 * d1 + d2 * d2;
#pragma unroll
  for (int off = 32; off > 0; off >>= 1) ss += __shfl_xor(ss, off, 64);
  float inv = rsqrtf(ss * (1.0f / 192.0f) + 1e-5f);
  p[lane] = f2bf(d0 * inv * g[lane] + bb[lane]);
  p[lane + 64] = f2bf(d1 * inv * g[lane + 64] + bb[lane + 64]);
  p[lane + 128] = f2bf(d2 * inv * g[lane + 128] + bb[lane + 128]);
}

// scatter anchor_tok into zeroed bf16 anchor_map
__global__ void scatter_kernel(const float* __restrict__ attout,
                               const int* __restrict__ idx,
                               ushortt* __restrict__ amap) {
  int bt = blockIdx.x;
  int b = bt >> 4, t = bt & 15;
  for (int e = threadIdx.x; e < KK * Aa; e += 256) {
    int k = e / Aa, a = e % Aa;
    int n = idx[bt * KK + k];
    amap[((size_t)bt * Nn + n) * Aa + a] =
        f2bf(attout[((size_t)(b * KK + k) * Tt + t) * Aa + a]);
  }
}

// gate MLP + 3-way softmax; one block per b, 192 threads
__global__ void gate_kernel(const float* __restrict__ dppart,
                            const float* __restrict__ appart,
                            const float* __restrict__ w1,
                            const float* __restrict__ b1,
                            const float* __restrict__ w2,
                            const float* __restrict__ b2,
                            float* __restrict__ gw) {
  int b = blockIdx.x;
  __shared__ float sg[2 * Aa];
  __shared__ float sh[Aa];
  int tid = threadIdx.x;
  {
    float d = 0.f;
    for (int t2 = 0; t2 < Tt; ++t2) d += dppart[(b * Tt + t2) * Aa + tid];
    sg[tid] = d * (1.0f / 3136.0f);
    float a = 0.f;
    for (int k2 = 0; k2 < KK; ++k2) a += appart[(b * KK + k2) * Aa + tid];
    sg[Aa + tid] = a * (1.0f / 128.0f);
  }
  __syncthreads();
  {
    const float* w = w1 + (size_t)tid * 2 * Aa;
    float s = b1[tid];
#pragma unroll 8
    for (int j = 0; j < 2 * Aa; ++j) s = fmaf(sg[j], w[j], s);
    sh[tid] = gelu_f(s);
  }
  __syncthreads();
  float v[3];
#pragma unroll
  for (int i = 0; i < 3; ++i) {
    const float* w = w2 + (size_t)(i * Aa + tid) * Aa;
    float s = b2[i * Aa + tid];
#pragma unroll 8
    for (int j = 0; j < Aa; ++j) s = fmaf(sh[j], w[j], s);
    v[i] = s;
  }
  float mx = fmaxf(v[0], fmaxf(v[1], v[2]));
  float e0 = expf(v[0] - mx), e1 = expf(v[1] - mx), e2 = expf(v[2] - mx);
  float inv = 1.0f / (e0 + e1 + e2);
  gw[(b * 3 + 0) * Aa + tid] = e0 * inv;
  gw[(b * 3 + 1) * Aa + tid] = e1 * inv;
  gw[(b * 3 + 2) * Aa + tid] = e2 * inv;
}

// fused = gw0*local + gw1*trans + gw2*amap (bf16 in/out); fmean fp32
__global__ void fused_kernel(const ushortt* __restrict__ local,
                             const ushortt* __restrict__ trans,
                             const ushortt* __restrict__ amap,
                             const float* __restrict__ gw,
                             ushortt* __restrict__ fused,
                             float* __restrict__ fmean) {
  int bt = blockIdx.x;
  int b = bt >> 4;
  int a = threadIdx.x;
  float g0 = gw[(b * 3 + 0) * Aa + a];
  float g1 = gw[(b * 3 + 1) * Aa + a];
  float g2 = gw[(b * 3 + 2) * Aa + a];
  size_t base = (size_t)bt * Nn * Aa + a;
  float acc = 0.f;
  for (int n = 0; n < Nn; ++n) {
    size_t o = base + (size_t)n * Aa;
    float f = g0 * bf2f(local[o]) + g1 * bf2f(trans[o]) + g2 * bf2f(amap[o]);
    fused[o] = f2bf(f);
    acc += f;
  }
  fmean[bt * Aa + a] = acc;
}

// cls_out = cls_tok + (mean_n fused) @ cls_w.T + cls_b
__global__ void cls_kernel(const float* __restrict__ fmean,
                           const float* __restrict__ cw,
                           const float* __restrict__ cb,
                           const float* __restrict__ x,
                           float* __restrict__ out) {
  int bt = blockIdx.x;
  __shared__ float fm[Aa];
  int tid = threadIdx.x;
  if (tid < Aa) fm[tid] = fmean[bt * Aa + tid] * (1.0f / 196.0f);
  __syncthreads();
  for (int c = tid; c < Cc; c += 256) {
    const float* w = cw + (size_t)c * Aa;
    float s = cb[c];
#pragma unroll 8
    for (int a = 0; a < Aa; ++a) s = fmaf(fm[a], w[a], s);
    size_t off = (size_t)bt * (Nn + 1) * Cc + c;
    out[off] = x[off] + s;
  }
}

// ============================================================
extern "C" void kernel_launch(void* const* d_in, const int* in_sizes, int n_in,
                              void* d_out, int out_size, void* d_ws,
                              size_t ws_size, hipStream_t stream) {
  const float* x = (const float*)d_in[0];
  const float* down_w = (const float*)d_in[1];
  const float* down_b = (const float*)d_in[2];
  const float* ldw_w = (const float*)d_in[3];
  const float* lpw_w = (const float*)d_in[4];
  const float* lnorm_g = (const float*)d_in[5];
  const float* lnorm_b = (const float*)d_in[6];
  const float* tdw_w = (const float*)d_in[7];
  const float* tpw_w = (const float*)d_in[8];
  const float* tmlp_w1 = (const float*)d_in[9];
  const float* tmlp_b1 = (const float*)d_in[10];
  const float* tmlp_w2 = (const float*)d_in[11];
  const float* tmlp_b2 = (const float*)d_in[12];
  const float* tnorm_g = (const float*)d_in[13];
  const float* tnorm_b = (const float*)d_in[14];
  const float* attn_in_w = (const float*)d_in[15];
  const float* attn_in_b = (const float*)d_in[16];
  const float* attn_out_w = (const float*)d_in[17];
  const float* attn_out_b = (const float*)d_in[18];
  const float* aproj_w = (const float*)d_in[19];
  const float* aproj_b = (const float*)d_in[20];
  const float* anorm_g = (const float*)d_in[21];
  const float* anorm_b = (const float*)d_in[22];
  const float* gate_w1 = (const float*)d_in[23];
  const float* gate_b1 = (const float*)d_in[24];
  const float* gate_w2 = (const float*)d_in[25];
  const float* gate_b2 = (const float*)d_in[26];
  const float* up_w = (const float*)d_in[27];
  const float* up_b = (const float*)d_in[28];
  const float* cls_w = (const float*)d_in[29];
  const float* cls_b = (const float*)d_in[30];
  float* out = (float*)d_out;

  float* ws = (float*)d_ws;
  float* W0 = ws;              // ph bf16 -> trp bf16 -> amap bf16
  float* W1 = W0 + SZ;         // delta bf16 -> transition bf16
  float* W2 = W1 + SZ;         // attn scratch -> locg/trg/h1/fused bf16
  float* W3 = W2 + 2 * SZ;     // local bf16
  float* sal = W3 + SZ;
  float* attout = sal + BTN;
  float* dppart = attout + (size_t)BKT * Aa;
  float* appart = dppart + (size_t)BT * Aa;
  float* gw = appart + (size_t)Bb * KK * Aa;
  float* fmean = gw + (size_t)Bb * 3 * Aa;
  double* sal64 = (double*)(fmean + (size_t)BT * Aa);  // BT*NCAND doubles
  int* cand = (int*)(sal64 + (size_t)BT * NCAND);      // BT*NCAND ints
  int* idx = cand + (size_t)BT * NCAND;                // BT*KK ints

  // bf16 views
  ushortt* ph_b    = (ushortt*)W0;
  ushortt* trp_b   = (ushortt*)W0;
  ushortt* amap_b  = (ushortt*)W0;
  ushortt* delta_b = (ushortt*)W1;
  ushortt* trans_b = (ushortt*)W1;
  ushortt* locg_b  = (ushortt*)W2;
  ushortt* trg_b   = (ushortt*)W2;
  ushortt* h1_b    = (ushortt*)W2;
  ushortt* fused_b = (ushortt*)W2;
  ushortt* local_b = (ushortt*)W3;

  // attn-phase scratch inside W2 (dead until conv2d)
  ushortt* tok_b = (ushortt*)W2;                       // 2048*192 bf16
  float* qkvb  = W2 + (size_t)BKT * Aa / 2;            // 2048*576 f32
  float* obuf  = qkvb + (size_t)BKT * 3 * Aa;          // 2048*192 f32
  float* proj1 = obuf + (size_t)BKT * Aa;              // 2048*192 f32

  // 1. ph = patch @ down_w.T + down_b (bf16 out)
  gemm_mfma<float, ushortt, 1, 1, 0><<<dim3(2, 392), 256, 0, stream>>>(
      x, down_w, down_b, ph_b, nullptr, BTN, Aa, Cc);
  // 2. delta + dp partials
  delta_kernel<<<BT, Aa, 0, stream>>>(ph_b, delta_b, dppart);
  // 3. saliency: fp32 candidates -> f64 refine -> exact top-8
  sal_kernel<<<BTN / 4, 256, 0, stream>>>(delta_b, sal);
  topcand_kernel<<<BT, 64, 0, stream>>>(sal, cand);
  refine_kernel<<<dim3(BT, NCAND), 192, 0, stream>>>(x, down_w, cand, sal64);
  select_kernel<<<BT, 64, 0, stream>>>(sal64, cand, idx);
  // 4. anchor attention
  gather_kernel<<<BKT, Aa, 0, stream>>>(ph_b, delta_b, idx, tok_b);
  gemm_mfma<ushortt, float, 0, 1, 0><<<dim3(6, 16), 256, 0, stream>>>(
      tok_b, attn_in_w, attn_in_b, qkvb, nullptr, BKT, 3 * Aa, Aa);
  attn_core<<<Bb * KK, 256, 0, stream>>>(qkvb, obuf);
  gemm_mfma<float, float, 0, 1, 0><<<dim3(2, 16), 256, 0, stream>>>(
      obuf, attn_out_w, attn_out_b, proj1, nullptr, BKT, Aa, Aa);
  gemm_mfma<float, float, 0, 1, 0><<<dim3(2, 16), 256, 0, stream>>>(
      proj1, aproj_w, aproj_b, attout, nullptr, BKT, Aa, Aa);
  appart_kernel<<<Bb * KK, Aa, 0, stream>>>(attout, appart);
  // 5. local branch
  conv2d_kernel<<<(unsigned)(SZ / 256), 256, 0, stream>>>(ph_b, ldw_w, locg_b);
  gemm_mfma<ushortt, ushortt, 0, 0, 0><<<dim3(2, 392), 256, 0, stream>>>(
      locg_b, lpw_w, nullptr, local_b, nullptr, BTN, Aa, Aa);
  ln_kernel<<<BTN / 4, 256, 0, stream>>>(local_b, lnorm_g, lnorm_b);
  // 6. transition branch
  conv1d_kernel<<<(unsigned)(SZ / 256), 256, 0, stream>>>(delta_b, tdw_w, trg_b);
  gemm_mfma<ushortt, ushortt, 0, 0, 0><<<dim3(2, 392), 256, 0, stream>>>(
      trg_b, tpw_w, nullptr, trp_b, nullptr, BTN, Aa, Aa);
  gemm_mfma<ushortt, ushortt, 0, 1, 1><<<dim3(4, 392), 256, 0, stream>>>(
      trp_b, tmlp_w1, tmlp_b1, h1_b, nullptr, BTN, 2 * Aa, Aa);
  gemm_mfma<ushortt, ushortt, 0, 1, 0><<<dim3(2, 392), 256, 0, stream>>>(
      h1_b, tmlp_w2, tmlp_b2, trans_b, nullptr, BTN, Aa, 2 * Aa);
  ln_kernel<<<BTN / 4, 256, 0, stream>>>(trans_b, tnorm_g, tnorm_b);
  // 7. anchor map
  hipMemsetAsync(amap_b, 0, SZ * sizeof(ushortt), stream);
  scatter_kernel<<<BT, 256, 0, stream>>>(attout, idx, amap_b);
  ln_kernel<<<BTN / 4, 256, 0, stream>>>(amap_b, anorm_g, anorm_b);
  // 8. gate
  gate_kernel<<<Bb, Aa, 0, stream>>>(dppart, appart, gate_w1, gate_b1,
                                     gate_w2, gate_b2, gw);
  // 9. fuse + output projections
  fused_kernel<<<BT, Aa, 0, stream>>>(local_b, trans_b, amap_b, gw, fused_b,
                                      fmean);
  gemm_mfma<ushortt, float, 0, 1, 2><<<dim3(8, 392), 256, 0, stream>>>(
      fused_b, up_w, up_b, out, x, BTN, Cc, Aa);
  cls_kernel<<<BT, 256, 0, stream>>>(fmean, cls_w, cls_b, x, out);
}

// Round 7
// 683.740 us; speedup vs baseline: 1.4903x; 1.4903x over previous
//
#include <hip/hip_runtime.h>
#include <math.h>

// ---- fixed problem dims ----
constexpr int Bb  = 16;
constexpr int Tt  = 16;
constexpr int Nn  = 196;   // patches (14x14)
constexpr int Cc  = 768;
constexpr int Aa  = 192;
constexpr int KK  = 8;     // TOPK
constexpr int NCAND = 16;  // fp32 candidates refined in f64
constexpr int BT  = Bb * Tt;            // 256
constexpr int BTN = BT * Nn;            // 50176
constexpr int BKT = Bb * KK * Tt;       // 2048 anchor-token rows
constexpr size_t SZ = (size_t)BTN * Aa; // 9,633,792 floats

typedef unsigned short ushortt;
typedef __attribute__((ext_vector_type(8))) short bf16x8;
typedef __attribute__((ext_vector_type(4))) float f32x4;
typedef __attribute__((ext_vector_type(4))) unsigned short u16x4;
typedef __attribute__((ext_vector_type(8))) unsigned short u16x8;

static __device__ __forceinline__ float gelu_f(float x) {
  return 0.5f * x * (1.0f + erff(x * 0.7071067811865476f));
}
static __device__ __forceinline__ ushortt f2bf(float f) {
  unsigned u = __float_as_uint(f);
  u += 0x7FFFu + ((u >> 16) & 1u);  // round-to-nearest-even
  return (ushortt)(u >> 16);
}
static __device__ __forceinline__ float bf2f(ushortt u) {
  return __uint_as_float(((unsigned)u) << 16);
}

// ============================================================
// bf16 MFMA GEMM: C[m,n] = sum_k A[m,k]*W[n,k] (+bias)(+epilogue)
// AT: float (staged->bf16) or ushort (bf16). CT: float or ushort.
// BM=128 BN=96 BK=32, 256 thr = 4 waves (2x2), wave tile 64x48
// (12 MFMA/step). EPI: 0 plain, 1 gelu, 2 mapped residual fp32.
// Grid (Nc/96, M/128); col-fastest + bijective XCD swizzle (nwg%8==0).
// ============================================================
template <typename AT, typename CT, int ROWMAP, int BIAS, int EPI>
__global__ __launch_bounds__(256) void gemm_mfma(
    const AT* __restrict__ Ain, const float* __restrict__ W,
    const float* __restrict__ bias, CT* __restrict__ Cout,
    const float* __restrict__ resid, int M, int Nc, int K) {
  constexpr int PIT = 40;  // bf16 pitch (32+8 pad) -> worst 2-way (free)
  __shared__ ushortt As[2][128 * PIT];
  __shared__ ushortt Bs[2][96 * PIT];
  const int tid = threadIdx.x;

  const int ncb = gridDim.x;
  const int nwg = ncb * gridDim.y;
  const int bid = blockIdx.y * ncb + blockIdx.x;
  const int cpx = nwg >> 3;
  const int swz = (bid & 7) * cpx + (bid >> 3);
  const int row0 = (swz / ncb) * 128;
  const int col0 = (swz % ncb) * 96;

  const int wid = tid >> 6;
  const int lane = tid & 63;
  const int wr = wid >> 1;       // 0..1 -> +64 rows
  const int wc = wid & 1;        // 0..1 -> +48 cols
  const int l15 = lane & 15;
  const int kgrp = lane >> 4;    // 0..3

  const int nsteps = K >> 5;

  const float* arowf[4];
  const ushortt* arowb[2];
  if constexpr (sizeof(AT) == 4) {
    const int srow = tid >> 3;
#pragma unroll
    for (int p = 0; p < 4; ++p) {
      int r = row0 + srow + 32 * p;
      if (ROWMAP) {
        int bt = r / Nn;
        int n = r - bt * Nn;
        arowf[p] = (const float*)Ain + (size_t)(bt * (Nn + 1) + 1 + n) * K;
      } else {
        arowf[p] = (const float*)Ain + (size_t)r * K;
      }
    }
  } else {
    const int srow2 = tid >> 2;
#pragma unroll
    for (int p = 0; p < 2; ++p)
      arowb[p] = (const ushortt*)Ain + (size_t)(row0 + srow2 + 64 * p) * K;
  }
  const float* browp[3];
  {
    const int srow = tid >> 3;
#pragma unroll
    for (int p = 0; p < 3; ++p)
      browp[p] = W + (size_t)(col0 + srow + 32 * p) * K;
  }

  f32x4 acc[4][3];
#pragma unroll
  for (int i = 0; i < 4; ++i)
#pragma unroll
    for (int j = 0; j < 3; ++j) acc[i][j] = (f32x4){0.f, 0.f, 0.f, 0.f};

  float4 apre[4], bpre[3];
  u16x8 apreb[2];

#define STAGE_LOAD(k0)                                                       \
  if constexpr (sizeof(AT) == 4) {                                           \
    const int quad = tid & 7;                                                \
    _Pragma("unroll") for (int p = 0; p < 4; ++p)                            \
        apre[p] = *(const float4*)(arowf[p] + (k0) + quad * 4);              \
  } else {                                                                   \
    const int quad2 = tid & 3;                                               \
    _Pragma("unroll") for (int p = 0; p < 2; ++p)                            \
        apreb[p] = *(const u16x8*)(arowb[p] + (k0) + quad2 * 8);             \
  }                                                                          \
  {                                                                          \
    const int quad = tid & 7;                                                \
    _Pragma("unroll") for (int p = 0; p < 3; ++p)                            \
        bpre[p] = *(const float4*)(browp[p] + (k0) + quad * 4);              \
  }

#define STAGE_WRITE(buf)                                                     \
  if constexpr (sizeof(AT) == 4) {                                           \
    const int quad = tid & 7, srow = tid >> 3;                               \
    _Pragma("unroll") for (int p = 0; p < 4; ++p) {                          \
      u16x4 b = {f2bf(apre[p].x), f2bf(apre[p].y), f2bf(apre[p].z),          \
                 f2bf(apre[p].w)};                                           \
      *(u16x4*)&As[buf][(srow + 32 * p) * PIT + quad * 4] = b;               \
    }                                                                        \
  } else {                                                                   \
    const int quad2 = tid & 3, srow2 = tid >> 2;                             \
    _Pragma("unroll") for (int p = 0; p < 2; ++p)                            \
        *(u16x8*)&As[buf][(srow2 + 64 * p) * PIT + quad2 * 8] = apreb[p];    \
  }                                                                          \
  {                                                                          \
    const int quad = tid & 7, srow = tid >> 3;                               \
    _Pragma("unroll") for (int p = 0; p < 3; ++p) {                          \
      u16x4 b = {f2bf(bpre[p].x), f2bf(bpre[p].y), f2bf(bpre[p].z),          \
                 f2bf(bpre[p].w)};                                           \
      *(u16x4*)&Bs[buf][(srow + 32 * p) * PIT + quad * 4] = b;               \
    }                                                                        \
  }

  STAGE_LOAD(0);
  STAGE_WRITE(0);
  __syncthreads();

  int cur = 0;
  for (int step = 0; step < nsteps; ++step) {
    const bool pref = (step + 1 < nsteps);
    if (pref) {
      int k0 = (step + 1) << 5;
      STAGE_LOAD(k0);
    }
    bf16x8 af[4], bfv[3];
#pragma unroll
    for (int fm = 0; fm < 4; ++fm)
      af[fm] = *(const bf16x8*)&As[cur][(wr * 64 + fm * 16 + l15) * PIT + kgrp * 8];
#pragma unroll
    for (int fn = 0; fn < 3; ++fn)
      bfv[fn] = *(const bf16x8*)&Bs[cur][(wc * 48 + fn * 16 + l15) * PIT + kgrp * 8];
#pragma unroll
    for (int fm = 0; fm < 4; ++fm)
#pragma unroll
      for (int fn = 0; fn < 3; ++fn)
        acc[fm][fn] = __builtin_amdgcn_mfma_f32_16x16x32_bf16(
            af[fm], bfv[fn], acc[fm][fn], 0, 0, 0);
    if (pref) {
      STAGE_WRITE(cur ^ 1);
    }
    __syncthreads();
    cur ^= 1;
  }
#undef STAGE_LOAD
#undef STAGE_WRITE

  // epilogue: C/D layout col=lane&15, row=(lane>>4)*4+j
#pragma unroll
  for (int fm = 0; fm < 4; ++fm) {
    int rbase = row0 + wr * 64 + fm * 16 + kgrp * 4;
#pragma unroll
    for (int fn = 0; fn < 3; ++fn) {
      int c = col0 + wc * 48 + fn * 16 + l15;
      float bv = BIAS ? bias[c] : 0.f;
#pragma unroll
      for (int j = 0; j < 4; ++j) {
        int r = rbase + j;
        float v = acc[fm][fn][j] + bv;
        if (EPI == 1) v = gelu_f(v);
        if (EPI == 2) {
          int bt = r / Nn;
          int n = r - bt * Nn;
          size_t off = (size_t)(bt * (Nn + 1) + 1 + n) * Nc + c;
          ((float*)Cout)[off] = resid[off] + v;
        } else {
          if constexpr (sizeof(CT) == 4)
            Cout[(size_t)r * Nc + c] = (CT)v;
          else
            ((ushortt*)Cout)[(size_t)r * Nc + c] = f2bf(v);
        }
      }
    }
  }
}

// ============================================================
// delta (bf16) + per-(b,t) |delta| partials
// ============================================================
__global__ void delta_kernel(const ushortt* __restrict__ ph,
                             ushortt* __restrict__ delta,
                             float* __restrict__ dppart) {
  int bt = blockIdx.x;
  int t = bt & 15;
  int a = threadIdx.x;
  const ushortt* cur = ph + (size_t)bt * Nn * Aa + a;
  ushortt* dl = delta + (size_t)bt * Nn * Aa + a;
  float acc = 0.f;
  if (t == 0) {
    for (int n = 0; n < Nn; ++n) dl[(size_t)n * Aa] = 0;
  } else {
    const ushortt* prev = cur - (size_t)Nn * Aa;
    for (int n = 0; n < Nn; ++n) {
      float d = bf2f(cur[(size_t)n * Aa]) - bf2f(prev[(size_t)n * Aa]);
      dl[(size_t)n * Aa] = f2bf(d);
      acc += fabsf(d);
    }
  }
  dppart[bt * Aa + a] = acc;
}

// sal[row] = mean_a |delta[row,a]| (fp32, candidate stage only)
__global__ void sal_kernel(const ushortt* __restrict__ delta,
                           float* __restrict__ sal) {
  int row = blockIdx.x * 4 + (threadIdx.x >> 6);
  int lane = threadIdx.x & 63;
  const ushortt* d = delta + (size_t)row * Aa;
  float s = fabsf(bf2f(d[lane])) + fabsf(bf2f(d[lane + 64])) +
            fabsf(bf2f(d[lane + 128]));
#pragma unroll
  for (int off = 32; off > 0; off >>= 1) s += __shfl_xor(s, off, 64);
  if (lane == 0) sal[row] = s * (1.0f / 192.0f);
}

// ============================================================
// top-16 fp32 candidates per (b,t); descending val, ties -> smaller n
// ============================================================
__global__ void topcand_kernel(const float* __restrict__ sal,
                               int* __restrict__ cand) {
  int bt = blockIdx.x;
  int lane = threadIdx.x;
  unsigned long long key[4];
#pragma unroll
  for (int j = 0; j < 4; ++j) {
    int n = lane + 64 * j;
    if (n < Nn) {
      unsigned fb = __float_as_uint(sal[(size_t)bt * Nn + n]);
      key[j] = ((unsigned long long)fb << 32) |
               (unsigned long long)(0xFFFFFFFFu - (unsigned)n);
    } else {
      key[j] = 0ULL;
    }
  }
  for (int r = 0; r < NCAND; ++r) {
    unsigned long long m = key[0];
    if (key[1] > m) m = key[1];
    if (key[2] > m) m = key[2];
    if (key[3] > m) m = key[3];
#pragma unroll
    for (int off = 32; off > 0; off >>= 1) {
      unsigned long long o = __shfl_xor(m, off, 64);
      if (o > m) m = o;
    }
    if (lane == 0)
      cand[bt * NCAND + r] = (int)(0xFFFFFFFFu - (unsigned)(m & 0xFFFFFFFFull));
#pragma unroll
    for (int j = 0; j < 4; ++j)
      if (key[j] == m) key[j] = 0ULL;
  }
}

// one-time transpose: wT[c][a] = down_w[a][c]
__global__ void transpose_w(const float* __restrict__ w,
                            float* __restrict__ wT) {
  int e = blockIdx.x * 256 + threadIdx.x;  // over Cc*Aa
  int c = e / Aa, a = e - c * Aa;
  wT[e] = w[(size_t)a * Cc + c];
}

// ============================================================
// f64 refine, 8 candidates per block (grid BT x 2, 192 thr).
// diff staged once in LDS (f64); w read COALESCED via wT[c][a]
// (lane = a -> consecutive addresses). 8 f64 FMA per c per thread.
// ============================================================
__global__ __launch_bounds__(192) void refine_kernel(
    const float* __restrict__ x, const float* __restrict__ wT,
    const int* __restrict__ cand, double* __restrict__ sal64) {
  int bt = blockIdx.x;
  int grp = blockIdx.y;
  int t = bt & 15;
  int a = threadIdx.x;
  if (t == 0) {
    if (a < 8) sal64[bt * NCAND + grp * 8 + a] = 0.0;
    return;
  }
  __shared__ double sdiff[8][Cc];  // 49 KB
  const float* xt = x + ((size_t)bt * (Nn + 1) + 1) * Cc;
  const float* xp = xt - (size_t)(Nn + 1) * Cc;
  for (int g = 0; g < 8; ++g) {
    int n = cand[bt * NCAND + grp * 8 + g];
    const float* rt = xt + (size_t)n * Cc;
    const float* rp = xp + (size_t)n * Cc;
    for (int c = a; c < Cc; c += 192)
      sdiff[g][c] = (double)rt[c] - (double)rp[c];
  }
  __syncthreads();
  double acc[8] = {};
  for (int c = 0; c < Cc; ++c) {
    double wv = (double)wT[(size_t)c * Aa + a];  // coalesced across lanes
#pragma unroll
    for (int g = 0; g < 8; ++g) acc[g] = fma(wv, sdiff[g][c], acc[g]);
  }
  __shared__ double part[3][8];
  int wvx = a >> 6, ln = a & 63;
#pragma unroll
  for (int g = 0; g < 8; ++g) {
    double v = fabs(acc[g]);
#pragma unroll
    for (int off = 32; off > 0; off >>= 1) v += __shfl_xor(v, off, 64);
    if (ln == 0) part[wvx][g] = v;
  }
  __syncthreads();
  if (a < 8) {
    double s = part[0][a] + part[1][a] + part[2][a];
    sal64[bt * NCAND + grp * 8 + a] = s * (1.0 / 192.0);
  }
}

// final top-8 by (sal64 desc, n asc)
__global__ void select_kernel(const double* __restrict__ sal64,
                              const int* __restrict__ cand,
                              int* __restrict__ idx) {
  int bt = blockIdx.x;
  int t = bt & 15;
  if (threadIdx.x != 0) return;
  if (t == 0) {
    for (int r = 0; r < KK; ++r) idx[bt * KK + r] = r;
    return;
  }
  double v[NCAND];
  int nn[NCAND];
  bool used[NCAND];
  for (int i = 0; i < NCAND; ++i) {
    v[i] = sal64[bt * NCAND + i];
    nn[i] = cand[bt * NCAND + i];
    used[i] = false;
  }
  for (int r = 0; r < KK; ++r) {
    int best = -1;
    for (int i = 0; i < NCAND; ++i) {
      if (used[i]) continue;
      if (best < 0 || v[i] > v[best] ||
          (v[i] == v[best] && nn[i] < nn[best]))
        best = i;
    }
    used[best] = true;
    idx[bt * KK + r] = nn[best];
  }
}

// ============================================================
// anchor attention: gather(bf16) -> GEMM qkv -> core -> GEMMs
// ============================================================
__global__ void gather_kernel(const ushortt* __restrict__ ph,
                              const ushortt* __restrict__ delta,
                              const int* __restrict__ idx,
                              ushortt* __restrict__ tok) {
  int row = blockIdx.x;  // (b*KK+k)*16+t
  int t = row & 15;
  int bk = row >> 4;
  int b = bk >> 3, k = bk & 7;
  int a = threadIdx.x;
  int n = idx[(b * 16 + t) * KK + k];
  size_t off = ((size_t)(b * 16 + t) * Nn + n) * Aa + a;
  tok[(size_t)row * Aa + a] = f2bf(bf2f(ph[off]) + bf2f(delta[off]));
}

__global__ __launch_bounds__(256) void attn_core(
    const float* __restrict__ qkv, float* __restrict__ o) {
  constexpr int P = 580;
  __shared__ float sq[16 * P];
  __shared__ float ssc[4][16][17];
  int bk = blockIdx.x;
  int tid = threadIdx.x;
  const float* src = qkv + (size_t)bk * 16 * 576;
  for (int e = tid; e < 16 * 144; e += 256) {
    int r = e / 144, c4 = e % 144;
    float4 v = *(const float4*)(src + r * 576 + c4 * 4);
    *(float4*)(&sq[r * P + c4 * 4]) = v;
  }
  __syncthreads();
  int h = tid >> 6, lane = tid & 63;
#pragma unroll
  for (int s4 = 0; s4 < 4; ++s4) {
    int e = lane + 64 * s4;
    int i = e >> 4, j = e & 15;
    const float* q = sq + i * P + h * 48;
    const float* k2 = sq + j * P + 192 + h * 48;
    float s = 0.f;
#pragma unroll
    for (int d = 0; d < 48; ++d) s = fmaf(q[d], k2[d], s);
    ssc[h][i][j] = s * 0.14433756729740643f;  // 1/sqrt(48)
  }
  __syncthreads();
  if (lane < 16) {
    float* r = ssc[h][lane];
    float mx = r[0];
    for (int j = 1; j < 16; ++j) mx = fmaxf(mx, r[j]);
    float sum = 0.f;
    for (int j = 0; j < 16; ++j) {
      float ev = expf(r[j] - mx);
      r[j] = ev;
      sum += ev;
    }
    float inv = 1.0f / sum;
    for (int j = 0; j < 16; ++j) r[j] *= inv;
  }
  __syncthreads();
#pragma unroll
  for (int s4 = 0; s4 < 12; ++s4) {
    int e = lane + 64 * s4;
    int i = e / 48, d = e - i * 48;
    float s = 0.f;
#pragma unroll
    for (int j = 0; j < 16; ++j)
      s = fmaf(ssc[h][i][j], sq[j * P + 384 + h * 48 + d], s);
    o[((size_t)bk * 16 + i) * 192 + h * 48 + d] = s;
  }
}

__global__ void appart_kernel(const float* __restrict__ attout,
                              float* __restrict__ appart) {
  int bk = blockIdx.x;
  int a = threadIdx.x;
  float s = 0.f;
  for (int t = 0; t < Tt; ++t)
    s += attout[((size_t)bk * Tt + t) * Aa + a];
  appart[bk * Aa + a] = s;
}

// depthwise 3x3 SAME conv over 14x14 + gelu; bf16 in/out
__global__ void conv2d_kernel(const ushortt* __restrict__ ph,
                              const float* __restrict__ ldw,
                              ushortt* __restrict__ og) {
  size_t e = (size_t)blockIdx.x * 256 + threadIdx.x;
  int a = (int)(e % Aa);
  size_t r = e / Aa;
  int n = (int)(r % Nn);
  int bt = (int)(r / Nn);
  int y = n / 14, x = n % 14;
  const ushortt* base = ph + (size_t)bt * Nn * Aa + a;
  const float* w = ldw + a * 9;
  float s = 0.f;
#pragma unroll
  for (int dy = -1; dy <= 1; ++dy) {
    int yy = y + dy;
    if (yy < 0 || yy >= 14) continue;
#pragma unroll
    for (int dx = -1; dx <= 1; ++dx) {
      int xc = x + dx;
      if (xc < 0 || xc >= 14) continue;
      s = fmaf(bf2f(base[(size_t)(yy * 14 + xc) * Aa]),
               w[(dy + 1) * 3 + (dx + 1)], s);
    }
  }
  og[e] = f2bf(gelu_f(s));
}

// depthwise k=3 SAME conv over t + gelu; bf16 in/out
__global__ void conv1d_kernel(const ushortt* __restrict__ delta,
                              const float* __restrict__ tdw,
                              ushortt* __restrict__ og) {
  size_t e = (size_t)blockIdx.x * 256 + threadIdx.x;
  int a = (int)(e % Aa);
  size_t r = e / Aa;
  int n = (int)(r % Nn);
  int bt = (int)(r / Nn);
  int t = bt & 15, b = bt >> 4;
  const float* w = tdw + a * 3;
  float s = 0.f;
#pragma unroll
  for (int j = 0; j < 3; ++j) {
    int tt = t + j - 1;
    if (tt >= 0 && tt < Tt)
      s = fmaf(bf2f(delta[((size_t)(b * Tt + tt) * Nn + n) * Aa + a]), w[j], s);
  }
  og[e] = f2bf(gelu_f(s));
}

// in-place LayerNorm over last dim (192); one wave per row (bf16)
__global__ void ln_kernel(ushortt* __restrict__ buf,
                          const float* __restrict__ g,
                          const float* __restrict__ bb) {
  size_t row = (size_t)blockIdx.x * 4 + (threadIdx.x >> 6);
  int lane = threadIdx.x & 63;
  ushortt* p = buf + row * Aa;
  float v0 = bf2f(p[lane]), v1 = bf2f(p[lane + 64]), v2 = bf2f(p[lane + 128]);
  float s = v0 + v1 + v2;
#pragma unroll
  for (int off = 32; off > 0; off >>= 1) s += __shfl_xor(s, off, 64);
  float m = s * (1.0f / 192.0f);
  float d0 = v0 - m, d1 = v1 - m, d2 = v2 - m;
  float ss = d0 * d0 + d1 * d1 + d2 * d2;
#pragma unroll
  for (int off = 32; off > 0; off >>= 1) ss += __shfl_xor(ss, off, 64);
  float inv = rsqrtf(ss * (1.0f / 192.0f) + 1e-5f);
  p[lane] = f2bf(d0 * inv * g[lane] + bb[lane]);
  p[lane + 64] = f2bf(d1 * inv * g[lane + 64] + bb[lane + 64]);
  p[lane + 128] = f2bf(d2 * inv * g[lane + 128] + bb[lane + 128]);
}

// scatter anchor_tok into zeroed bf16 anchor_map
__global__ void scatter_kernel(const float* __restrict__ attout,
                               const int* __restrict__ idx,
                               ushortt* __restrict__ amap) {
  int bt = blockIdx.x;
  int b = bt >> 4, t = bt & 15;
  for (int e = threadIdx.x; e < KK * Aa; e += 256) {
    int k = e / Aa, a = e % Aa;
    int n = idx[bt * KK + k];
    amap[((size_t)bt * Nn + n) * Aa + a] =
        f2bf(attout[((size_t)(b * KK + k) * Tt + t) * Aa + a]);
  }
}

// gate MLP + 3-way softmax; one block per b, 192 threads
__global__ void gate_kernel(const float* __restrict__ dppart,
                            const float* __restrict__ appart,
                            const float* __restrict__ w1,
                            const float* __restrict__ b1,
                            const float* __restrict__ w2,
                            const float* __restrict__ b2,
                            float* __restrict__ gw) {
  int b = blockIdx.x;
  __shared__ float sg[2 * Aa];
  __shared__ float sh[Aa];
  int tid = threadIdx.x;
  {
    float d = 0.f;
    for (int t2 = 0; t2 < Tt; ++t2) d += dppart[(b * Tt + t2) * Aa + tid];
    sg[tid] = d * (1.0f / 3136.0f);
    float a = 0.f;
    for (int k2 = 0; k2 < KK; ++k2) a += appart[(b * KK + k2) * Aa + tid];
    sg[Aa + tid] = a * (1.0f / 128.0f);
  }
  __syncthreads();
  {
    const float* w = w1 + (size_t)tid * 2 * Aa;
    float s = b1[tid];
#pragma unroll 8
    for (int j = 0; j < 2 * Aa; ++j) s = fmaf(sg[j], w[j], s);
    sh[tid] = gelu_f(s);
  }
  __syncthreads();
  float v[3];
#pragma unroll
  for (int i = 0; i < 3; ++i) {
    const float* w = w2 + (size_t)(i * Aa + tid) * Aa;
    float s = b2[i * Aa + tid];
#pragma unroll 8
    for (int j = 0; j < Aa; ++j) s = fmaf(sh[j], w[j], s);
    v[i] = s;
  }
  float mx = fmaxf(v[0], fmaxf(v[1], v[2]));
  float e0 = expf(v[0] - mx), e1 = expf(v[1] - mx), e2 = expf(v[2] - mx);
  float inv = 1.0f / (e0 + e1 + e2);
  gw[(b * 3 + 0) * Aa + tid] = e0 * inv;
  gw[(b * 3 + 1) * Aa + tid] = e1 * inv;
  gw[(b * 3 + 2) * Aa + tid] = e2 * inv;
}

// fused = gw0*local + gw1*trans + gw2*amap (bf16 in/out); fmean fp32
__global__ void fused_kernel(const ushortt* __restrict__ local,
                             const ushortt* __restrict__ trans,
                             const ushortt* __restrict__ amap,
                             const float* __restrict__ gw,
                             ushortt* __restrict__ fused,
                             float* __restrict__ fmean) {
  int bt = blockIdx.x;
  int b = bt >> 4;
  int a = threadIdx.x;
  float g0 = gw[(b * 3 + 0) * Aa + a];
  float g1 = gw[(b * 3 + 1) * Aa + a];
  float g2 = gw[(b * 3 + 2) * Aa + a];
  size_t base = (size_t)bt * Nn * Aa + a;
  float acc = 0.f;
  for (int n = 0; n < Nn; ++n) {
    size_t o = base + (size_t)n * Aa;
    float f = g0 * bf2f(local[o]) + g1 * bf2f(trans[o]) + g2 * bf2f(amap[o]);
    fused[o] = f2bf(f);
    acc += f;
  }
  fmean[bt * Aa + a] = acc;
}

// cls_out = cls_tok + (mean_n fused) @ cls_w.T + cls_b
__global__ void cls_kernel(const float* __restrict__ fmean,
                           const float* __restrict__ cw,
                           const float* __restrict__ cb,
                           const float* __restrict__ x,
                           float* __restrict__ out) {
  int bt = blockIdx.x;
  __shared__ float fm[Aa];
  int tid = threadIdx.x;
  if (tid < Aa) fm[tid] = fmean[bt * Aa + tid] * (1.0f / 196.0f);
  __syncthreads();
  for (int c = tid; c < Cc; c += 256) {
    const float* w = cw + (size_t)c * Aa;
    float s = cb[c];
#pragma unroll 8
    for (int a = 0; a < Aa; ++a) s = fmaf(fm[a], w[a], s);
    size_t off = (size_t)bt * (Nn + 1) * Cc + c;
    out[off] = x[off] + s;
  }
}

// ============================================================
extern "C" void kernel_launch(void* const* d_in, const int* in_sizes, int n_in,
                              void* d_out, int out_size, void* d_ws,
                              size_t ws_size, hipStream_t stream) {
  const float* x = (const float*)d_in[0];
  const float* down_w = (const float*)d_in[1];
  const float* down_b = (const float*)d_in[2];
  const float* ldw_w = (const float*)d_in[3];
  const float* lpw_w = (const float*)d_in[4];
  const float* lnorm_g = (const float*)d_in[5];
  const float* lnorm_b = (const float*)d_in[6];
  const float* tdw_w = (const float*)d_in[7];
  const float* tpw_w = (const float*)d_in[8];
  const float* tmlp_w1 = (const float*)d_in[9];
  const float* tmlp_b1 = (const float*)d_in[10];
  const float* tmlp_w2 = (const float*)d_in[11];
  const float* tmlp_b2 = (const float*)d_in[12];
  const float* tnorm_g = (const float*)d_in[13];
  const float* tnorm_b = (const float*)d_in[14];
  const float* attn_in_w = (const float*)d_in[15];
  const float* attn_in_b = (const float*)d_in[16];
  const float* attn_out_w = (const float*)d_in[17];
  const float* attn_out_b = (const float*)d_in[18];
  const float* aproj_w = (const float*)d_in[19];
  const float* aproj_b = (const float*)d_in[20];
  const float* anorm_g = (const float*)d_in[21];
  const float* anorm_b = (const float*)d_in[22];
  const float* gate_w1 = (const float*)d_in[23];
  const float* gate_b1 = (const float*)d_in[24];
  const float* gate_w2 = (const float*)d_in[25];
  const float* gate_b2 = (const float*)d_in[26];
  const float* up_w = (const float*)d_in[27];
  const float* up_b = (const float*)d_in[28];
  const float* cls_w = (const float*)d_in[29];
  const float* cls_b = (const float*)d_in[30];
  float* out = (float*)d_out;

  float* ws = (float*)d_ws;
  float* W0 = ws;              // ph bf16 -> trp bf16 -> amap bf16
  float* W1 = W0 + SZ;         // delta bf16 -> transition bf16
  float* W2 = W1 + SZ;         // attn scratch -> locg/trg/h1/fused bf16
  float* W3 = W2 + 2 * SZ;     // local bf16
  float* sal = W3 + SZ;
  float* attout = sal + BTN;
  float* dppart = attout + (size_t)BKT * Aa;
  float* appart = dppart + (size_t)BT * Aa;
  float* gw = appart + (size_t)Bb * KK * Aa;
  float* fmean = gw + (size_t)Bb * 3 * Aa;
  double* sal64 = (double*)(fmean + (size_t)BT * Aa);  // BT*NCAND doubles
  int* cand = (int*)(sal64 + (size_t)BT * NCAND);      // BT*NCAND ints
  int* idx = cand + (size_t)BT * NCAND;                // BT*KK ints
  float* wT = (float*)(idx + (size_t)BT * KK);         // Cc*Aa floats

  // bf16 views
  ushortt* ph_b    = (ushortt*)W0;
  ushortt* trp_b   = (ushortt*)W0;
  ushortt* amap_b  = (ushortt*)W0;
  ushortt* delta_b = (ushortt*)W1;
  ushortt* trans_b = (ushortt*)W1;
  ushortt* locg_b  = (ushortt*)W2;
  ushortt* trg_b   = (ushortt*)W2;
  ushortt* h1_b    = (ushortt*)W2;
  ushortt* fused_b = (ushortt*)W2;
  ushortt* local_b = (ushortt*)W3;

  // attn-phase scratch inside W2 (dead until conv2d)
  ushortt* tok_b = (ushortt*)W2;                       // 2048*192 bf16
  float* qkvb  = W2 + (size_t)BKT * Aa / 2;            // 2048*576 f32
  float* obuf  = qkvb + (size_t)BKT * 3 * Aa;          // 2048*192 f32
  float* proj1 = obuf + (size_t)BKT * Aa;              // 2048*192 f32

  // 1. ph = patch @ down_w.T + down_b (bf16 out)
  gemm_mfma<float, ushortt, 1, 1, 0><<<dim3(2, 392), 256, 0, stream>>>(
      x, down_w, down_b, ph_b, nullptr, BTN, Aa, Cc);
  transpose_w<<<(Cc * Aa) / 256, 256, 0, stream>>>(down_w, wT);
  // 2. delta + dp partials
  delta_kernel<<<BT, Aa, 0, stream>>>(ph_b, delta_b, dppart);
  // 3. saliency: fp32 candidates -> f64 refine -> exact top-8
  sal_kernel<<<BTN / 4, 256, 0, stream>>>(delta_b, sal);
  topcand_kernel<<<BT, 64, 0, stream>>>(sal, cand);
  refine_kernel<<<dim3(BT, 2), 192, 0, stream>>>(x, wT, cand, sal64);
  select_kernel<<<BT, 64, 0, stream>>>(sal64, cand, idx);
  // 4. anchor attention
  gather_kernel<<<BKT, Aa, 0, stream>>>(ph_b, delta_b, idx, tok_b);
  gemm_mfma<ushortt, float, 0, 1, 0><<<dim3(6, 16), 256, 0, stream>>>(
      tok_b, attn_in_w, attn_in_b, qkvb, nullptr, BKT, 3 * Aa, Aa);
  attn_core<<<Bb * KK, 256, 0, stream>>>(qkvb, obuf);
  gemm_mfma<float, float, 0, 1, 0><<<dim3(2, 16), 256, 0, stream>>>(
      obuf, attn_out_w, attn_out_b, proj1, nullptr, BKT, Aa, Aa);
  gemm_mfma<float, float, 0, 1, 0><<<dim3(2, 16), 256, 0, stream>>>(
      proj1, aproj_w, aproj_b, attout, nullptr, BKT, Aa, Aa);
  appart_kernel<<<Bb * KK, Aa, 0, stream>>>(attout, appart);
  // 5. local branch
  conv2d_kernel<<<(unsigned)(SZ / 256), 256, 0, stream>>>(ph_b, ldw_w, locg_b);
  gemm_mfma<ushortt, ushortt, 0, 0, 0><<<dim3(2, 392), 256, 0, stream>>>(
      locg_b, lpw_w, nullptr, local_b, nullptr, BTN, Aa, Aa);
  ln_kernel<<<BTN / 4, 256, 0, stream>>>(local_b, lnorm_g, lnorm_b);
  // 6. transition branch
  conv1d_kernel<<<(unsigned)(SZ / 256), 256, 0, stream>>>(delta_b, tdw_w, trg_b);
  gemm_mfma<ushortt, ushortt, 0, 0, 0><<<dim3(2, 392), 256, 0, stream>>>(
      trg_b, tpw_w, nullptr, trp_b, nullptr, BTN, Aa, Aa);
  gemm_mfma<ushortt, ushortt, 0, 1, 1><<<dim3(4, 392), 256, 0, stream>>>(
      trp_b, tmlp_w1, tmlp_b1, h1_b, nullptr, BTN, 2 * Aa, Aa);
  gemm_mfma<ushortt, ushortt, 0, 1, 0><<<dim3(2, 392), 256, 0, stream>>>(
      h1_b, tmlp_w2, tmlp_b2, trans_b, nullptr, BTN, Aa, 2 * Aa);
  ln_kernel<<<BTN / 4, 256, 0, stream>>>(trans_b, tnorm_g, tnorm_b);
  // 7. anchor map
  hipMemsetAsync(amap_b, 0, SZ * sizeof(ushortt), stream);
  scatter_kernel<<<BT, 256, 0, stream>>>(attout, idx, amap_b);
  ln_kernel<<<BTN / 4, 256, 0, stream>>>(amap_b, anorm_g, anorm_b);
  // 8. gate
  gate_kernel<<<Bb, Aa, 0, stream>>>(dppart, appart, gate_w1, gate_b1,
                                     gate_w2, gate_b2, gw);
  // 9. fuse + output projections
  fused_kernel<<<BT, Aa, 0, stream>>>(local_b, trans_b, amap_b, gw, fused_b,
                                      fmean);
  gemm_mfma<ushortt, float, 0, 1, 2><<<dim3(8, 392), 256, 0, stream>>>(
      fused_b, up_w, up_b, out, x, BTN, Cc, Aa);
  cls_kernel<<<BT, 256, 0, stream>>>(fmean, cls_w, cls_b, x, out);
}

// Round 8
// 682.125 us; speedup vs baseline: 1.4938x; 1.0024x over previous
//
#include <hip/hip_runtime.h>
#include <math.h>

// ---- fixed problem dims ----
constexpr int Bb  = 16;
constexpr int Tt  = 16;
constexpr int Nn  = 196;   // patches (14x14)
constexpr int Cc  = 768;
constexpr int Aa  = 192;
constexpr int KK  = 8;     // TOPK
constexpr int NCAND = 16;  // fp32 candidates refined in f64
constexpr int BT  = Bb * Tt;            // 256
constexpr int BTN = BT * Nn;            // 50176
constexpr int BKT = Bb * KK * Tt;       // 2048 anchor-token rows
constexpr size_t SZ = (size_t)BTN * Aa; // 9,633,792 floats

typedef unsigned short ushortt;
typedef __attribute__((ext_vector_type(8))) short bf16x8;
typedef __attribute__((ext_vector_type(4))) float f32x4;
typedef __attribute__((ext_vector_type(4))) unsigned short u16x4;
typedef __attribute__((ext_vector_type(8))) unsigned short u16x8;

static __device__ __forceinline__ float gelu_f(float x) {
  return 0.5f * x * (1.0f + erff(x * 0.7071067811865476f));
}
static __device__ __forceinline__ ushortt f2bf(float f) {
  unsigned u = __float_as_uint(f);
  u += 0x7FFFu + ((u >> 16) & 1u);  // round-to-nearest-even
  return (ushortt)(u >> 16);
}
static __device__ __forceinline__ float bf2f(ushortt u) {
  return __uint_as_float(((unsigned)u) << 16);
}

// ============================================================
// bf16 MFMA GEMM: C[m,n] = sum_k A[m,k]*W[n,k] (+bias)(+epilogue)
// AT: float (staged->bf16) or ushort (bf16). CT: float or ushort.
// BM=128 BN=96 BK=32, 256 thr = 4 waves (2x2), wave tile 64x48.
// EPI: 0 plain, 1 gelu, 2 mapped residual fp32.
// LDS-staged epilogue: acc -> LDS fp32 half-tile -> coalesced stores.
// Grid (Nc/96, M/128); col-fastest + bijective XCD swizzle (nwg%8==0).
// ============================================================
template <typename AT, typename CT, int ROWMAP, int BIAS, int EPI>
__global__ __launch_bounds__(256) void gemm_mfma(
    const AT* __restrict__ Ain, const float* __restrict__ W,
    const float* __restrict__ bias, CT* __restrict__ Cout,
    const float* __restrict__ resid, int M, int Nc, int K) {
  constexpr int PIT = 40;  // bf16 pitch (32+8 pad) -> worst 2-way (free)
  __shared__ __align__(16) unsigned char smem[(2 * 128 * PIT + 2 * 96 * PIT) * 2];
  ushortt (*As)[128 * PIT] = (ushortt(*)[128 * PIT])smem;
  ushortt (*Bs)[96 * PIT] =
      (ushortt(*)[96 * PIT])(smem + 2 * 128 * PIT * 2);
  const int tid = threadIdx.x;

  const int ncb = gridDim.x;
  const int nwg = ncb * gridDim.y;
  const int bid = blockIdx.y * ncb + blockIdx.x;
  const int cpx = nwg >> 3;
  const int swz = (bid & 7) * cpx + (bid >> 3);
  const int row0 = (swz / ncb) * 128;
  const int col0 = (swz % ncb) * 96;

  const int wid = tid >> 6;
  const int lane = tid & 63;
  const int wr = wid >> 1;       // 0..1 -> +64 rows
  const int wc = wid & 1;        // 0..1 -> +48 cols
  const int l15 = lane & 15;
  const int kgrp = lane >> 4;    // 0..3

  const int nsteps = K >> 5;

  const float* arowf[4];
  const ushortt* arowb[2];
  if constexpr (sizeof(AT) == 4) {
    const int srow = tid >> 3;
#pragma unroll
    for (int p = 0; p < 4; ++p) {
      int r = row0 + srow + 32 * p;
      if (ROWMAP) {
        int bt = r / Nn;
        int n = r - bt * Nn;
        arowf[p] = (const float*)Ain + (size_t)(bt * (Nn + 1) + 1 + n) * K;
      } else {
        arowf[p] = (const float*)Ain + (size_t)r * K;
      }
    }
  } else {
    const int srow2 = tid >> 2;
#pragma unroll
    for (int p = 0; p < 2; ++p)
      arowb[p] = (const ushortt*)Ain + (size_t)(row0 + srow2 + 64 * p) * K;
  }
  const float* browp[3];
  {
    const int srow = tid >> 3;
#pragma unroll
    for (int p = 0; p < 3; ++p)
      browp[p] = W + (size_t)(col0 + srow + 32 * p) * K;
  }

  f32x4 acc[4][3];
#pragma unroll
  for (int i = 0; i < 4; ++i)
#pragma unroll
    for (int j = 0; j < 3; ++j) acc[i][j] = (f32x4){0.f, 0.f, 0.f, 0.f};

  float4 apre[4], bpre[3];
  u16x8 apreb[2];

#define STAGE_LOAD(k0)                                                       \
  if constexpr (sizeof(AT) == 4) {                                           \
    const int quad = tid & 7;                                                \
    _Pragma("unroll") for (int p = 0; p < 4; ++p)                            \
        apre[p] = *(const float4*)(arowf[p] + (k0) + quad * 4);              \
  } else {                                                                   \
    const int quad2 = tid & 3;                                               \
    _Pragma("unroll") for (int p = 0; p < 2; ++p)                            \
        apreb[p] = *(const u16x8*)(arowb[p] + (k0) + quad2 * 8);             \
  }                                                                          \
  {                                                                          \
    const int quad = tid & 7;                                                \
    _Pragma("unroll") for (int p = 0; p < 3; ++p)                            \
        bpre[p] = *(const float4*)(browp[p] + (k0) + quad * 4);              \
  }

#define STAGE_WRITE(buf)                                                     \
  if constexpr (sizeof(AT) == 4) {                                           \
    const int quad = tid & 7, srow = tid >> 3;                               \
    _Pragma("unroll") for (int p = 0; p < 4; ++p) {                          \
      u16x4 b = {f2bf(apre[p].x), f2bf(apre[p].y), f2bf(apre[p].z),          \
                 f2bf(apre[p].w)};                                           \
      *(u16x4*)&As[buf][(srow + 32 * p) * PIT + quad * 4] = b;               \
    }                                                                        \
  } else {                                                                   \
    const int quad2 = tid & 3, srow2 = tid >> 2;                             \
    _Pragma("unroll") for (int p = 0; p < 2; ++p)                            \
        *(u16x8*)&As[buf][(srow2 + 64 * p) * PIT + quad2 * 8] = apreb[p];    \
  }                                                                          \
  {                                                                          \
    const int quad = tid & 7, srow = tid >> 3;                               \
    _Pragma("unroll") for (int p = 0; p < 3; ++p) {                          \
      u16x4 b = {f2bf(bpre[p].x), f2bf(bpre[p].y), f2bf(bpre[p].z),          \
                 f2bf(bpre[p].w)};                                           \
      *(u16x4*)&Bs[buf][(srow + 32 * p) * PIT + quad * 4] = b;               \
    }                                                                        \
  }

  STAGE_LOAD(0);
  STAGE_WRITE(0);
  __syncthreads();

  int cur = 0;
  for (int step = 0; step < nsteps; ++step) {
    const bool pref = (step + 1 < nsteps);
    if (pref) {
      int k0 = (step + 1) << 5;
      STAGE_LOAD(k0);
    }
    bf16x8 af[4], bfv[3];
#pragma unroll
    for (int fm = 0; fm < 4; ++fm)
      af[fm] = *(const bf16x8*)&As[cur][(wr * 64 + fm * 16 + l15) * PIT + kgrp * 8];
#pragma unroll
    for (int fn = 0; fn < 3; ++fn)
      bfv[fn] = *(const bf16x8*)&Bs[cur][(wc * 48 + fn * 16 + l15) * PIT + kgrp * 8];
#pragma unroll
    for (int fm = 0; fm < 4; ++fm)
#pragma unroll
      for (int fn = 0; fn < 3; ++fn)
        acc[fm][fn] = __builtin_amdgcn_mfma_f32_16x16x32_bf16(
            af[fm], bfv[fn], acc[fm][fn], 0, 0, 0);
    if (pref) {
      STAGE_WRITE(cur ^ 1);
    }
    __syncthreads();
    cur ^= 1;
  }
#undef STAGE_LOAD
#undef STAGE_WRITE

  // ---- LDS-staged epilogue: coalesced global stores ----
  constexpr int EP = 100;  // fp32 pitch for 96 cols (+4 pad)
  float* epi = (float*)smem;  // 64*100*4 = 25.6 KB <= 35.8 KB
  for (int h = 0; h < 2; ++h) {
    __syncthreads();
    if (wr == h) {
#pragma unroll
      for (int fm = 0; fm < 4; ++fm) {
        int rl = fm * 16 + kgrp * 4;
#pragma unroll
        for (int fn = 0; fn < 3; ++fn) {
          int cl = wc * 48 + fn * 16 + l15;
#pragma unroll
          for (int j = 0; j < 4; ++j)
            epi[(rl + j) * EP + cl] = acc[fm][fn][j];
        }
      }
    }
    __syncthreads();
#pragma unroll
    for (int it = 0; it < 6; ++it) {
      int f = it * 256 + tid;        // 0..1535 over 64 rows x 24 float4
      int r = f / 24, c4 = f - r * 24;
      float4 v = *(const float4*)&epi[r * EP + c4 * 4];
      int c = col0 + c4 * 4;
      if (BIAS) {
        float4 bv = *(const float4*)(bias + c);
        v.x += bv.x; v.y += bv.y; v.z += bv.z; v.w += bv.w;
      }
      if (EPI == 1) {
        v.x = gelu_f(v.x); v.y = gelu_f(v.y);
        v.z = gelu_f(v.z); v.w = gelu_f(v.w);
      }
      int R = row0 + h * 64 + r;
      if constexpr (EPI == 2) {
        int bt2 = R / Nn, n2 = R - bt2 * Nn;
        size_t off = (size_t)(bt2 * (Nn + 1) + 1 + n2) * Nc + c;
        float4 rv = *(const float4*)(resid + off);
        v.x += rv.x; v.y += rv.y; v.z += rv.z; v.w += rv.w;
        *(float4*)((float*)Cout + off) = v;
      } else if constexpr (sizeof(CT) == 4) {
        *(float4*)((float*)Cout + (size_t)R * Nc + c) = v;
      } else {
        u16x4 ob = {f2bf(v.x), f2bf(v.y), f2bf(v.z), f2bf(v.w)};
        *(u16x4*)((ushortt*)Cout + (size_t)R * Nc + c) = ob;
      }
    }
  }
}

// ============================================================
// delta (bf16) + per-(b,t) |delta| partials
// ============================================================
__global__ void delta_kernel(const ushortt* __restrict__ ph,
                             ushortt* __restrict__ delta,
                             float* __restrict__ dppart) {
  int bt = blockIdx.x;
  int t = bt & 15;
  int a = threadIdx.x;
  const ushortt* cur = ph + (size_t)bt * Nn * Aa + a;
  ushortt* dl = delta + (size_t)bt * Nn * Aa + a;
  float acc = 0.f;
  if (t == 0) {
    for (int n = 0; n < Nn; ++n) dl[(size_t)n * Aa] = 0;
  } else {
    const ushortt* prev = cur - (size_t)Nn * Aa;
    for (int n = 0; n < Nn; ++n) {
      float d = bf2f(cur[(size_t)n * Aa]) - bf2f(prev[(size_t)n * Aa]);
      dl[(size_t)n * Aa] = f2bf(d);
      acc += fabsf(d);
    }
  }
  dppart[bt * Aa + a] = acc;
}

// sal[row] = mean_a |delta[row,a]| (fp32, candidate stage only)
__global__ void sal_kernel(const ushortt* __restrict__ delta,
                           float* __restrict__ sal) {
  int row = blockIdx.x * 4 + (threadIdx.x >> 6);
  int lane = threadIdx.x & 63;
  const ushortt* d = delta + (size_t)row * Aa;
  float s = fabsf(bf2f(d[lane])) + fabsf(bf2f(d[lane + 64])) +
            fabsf(bf2f(d[lane + 128]));
#pragma unroll
  for (int off = 32; off > 0; off >>= 1) s += __shfl_xor(s, off, 64);
  if (lane == 0) sal[row] = s * (1.0f / 192.0f);
}

// ============================================================
// top-16 fp32 candidates per (b,t); descending val, ties -> smaller n
// ============================================================
__global__ void topcand_kernel(const float* __restrict__ sal,
                               int* __restrict__ cand) {
  int bt = blockIdx.x;
  int lane = threadIdx.x;
  unsigned long long key[4];
#pragma unroll
  for (int j = 0; j < 4; ++j) {
    int n = lane + 64 * j;
    if (n < Nn) {
      unsigned fb = __float_as_uint(sal[(size_t)bt * Nn + n]);
      key[j] = ((unsigned long long)fb << 32) |
               (unsigned long long)(0xFFFFFFFFu - (unsigned)n);
    } else {
      key[j] = 0ULL;
    }
  }
  for (int r = 0; r < NCAND; ++r) {
    unsigned long long m = key[0];
    if (key[1] > m) m = key[1];
    if (key[2] > m) m = key[2];
    if (key[3] > m) m = key[3];
#pragma unroll
    for (int off = 32; off > 0; off >>= 1) {
      unsigned long long o = __shfl_xor(m, off, 64);
      if (o > m) m = o;
    }
    if (lane == 0)
      cand[bt * NCAND + r] = (int)(0xFFFFFFFFu - (unsigned)(m & 0xFFFFFFFFull));
#pragma unroll
    for (int j = 0; j < 4; ++j)
      if (key[j] == m) key[j] = 0ULL;
  }
}

// one-time transpose: wT[c][a] = down_w[a][c]
__global__ void transpose_w(const float* __restrict__ w,
                            float* __restrict__ wT) {
  int e = blockIdx.x * 256 + threadIdx.x;  // over Cc*Aa
  int c = e / Aa, a = e - c * Aa;
  wT[e] = w[(size_t)a * Cc + c];
}

// ============================================================
// f64 refine, 8 candidates per block (grid BT x 2, 192 thr).
// diff staged once in LDS (f64); w read COALESCED via wT[c][a].
// ============================================================
__global__ __launch_bounds__(192) void refine_kernel(
    const float* __restrict__ x, const float* __restrict__ wT,
    const int* __restrict__ cand, double* __restrict__ sal64) {
  int bt = blockIdx.x;
  int grp = blockIdx.y;
  int t = bt & 15;
  int a = threadIdx.x;
  if (t == 0) {
    if (a < 8) sal64[bt * NCAND + grp * 8 + a] = 0.0;
    return;
  }
  __shared__ double sdiff[8][Cc];  // 49 KB
  const float* xt = x + ((size_t)bt * (Nn + 1) + 1) * Cc;
  const float* xp = xt - (size_t)(Nn + 1) * Cc;
  for (int g = 0; g < 8; ++g) {
    int n = cand[bt * NCAND + grp * 8 + g];
    const float* rt = xt + (size_t)n * Cc;
    const float* rp = xp + (size_t)n * Cc;
    for (int c = a; c < Cc; c += 192)
      sdiff[g][c] = (double)rt[c] - (double)rp[c];
  }
  __syncthreads();
  double acc[8] = {};
  for (int c = 0; c < Cc; ++c) {
    double wv = (double)wT[(size_t)c * Aa + a];  // coalesced across lanes
#pragma unroll
    for (int g = 0; g < 8; ++g) acc[g] = fma(wv, sdiff[g][c], acc[g]);
  }
  __shared__ double part[3][8];
  int wvx = a >> 6, ln = a & 63;
#pragma unroll
  for (int g = 0; g < 8; ++g) {
    double v = fabs(acc[g]);
#pragma unroll
    for (int off = 32; off > 0; off >>= 1) v += __shfl_xor(v, off, 64);
    if (ln == 0) part[wvx][g] = v;
  }
  __syncthreads();
  if (a < 8) {
    double s = part[0][a] + part[1][a] + part[2][a];
    sal64[bt * NCAND + grp * 8 + a] = s * (1.0 / 192.0);
  }
}

// final top-8 by (sal64 desc, n asc)
__global__ void select_kernel(const double* __restrict__ sal64,
                              const int* __restrict__ cand,
                              int* __restrict__ idx) {
  int bt = blockIdx.x;
  int t = bt & 15;
  if (threadIdx.x != 0) return;
  if (t == 0) {
    for (int r = 0; r < KK; ++r) idx[bt * KK + r] = r;
    return;
  }
  double v[NCAND];
  int nn[NCAND];
  bool used[NCAND];
  for (int i = 0; i < NCAND; ++i) {
    v[i] = sal64[bt * NCAND + i];
    nn[i] = cand[bt * NCAND + i];
    used[i] = false;
  }
  for (int r = 0; r < KK; ++r) {
    int best = -1;
    for (int i = 0; i < NCAND; ++i) {
      if (used[i]) continue;
      if (best < 0 || v[i] > v[best] ||
          (v[i] == v[best] && nn[i] < nn[best]))
        best = i;
    }
    used[best] = true;
    idx[bt * KK + r] = nn[best];
  }
}

// ============================================================
// anchor attention: gather(bf16) -> GEMM qkv -> core -> GEMMs
// ============================================================
__global__ void gather_kernel(const ushortt* __restrict__ ph,
                              const ushortt* __restrict__ delta,
                              const int* __restrict__ idx,
                              ushortt* __restrict__ tok) {
  int row = blockIdx.x;  // (b*KK+k)*16+t
  int t = row & 15;
  int bk = row >> 4;
  int b = bk >> 3, k = bk & 7;
  int a = threadIdx.x;
  int n = idx[(b * 16 + t) * KK + k];
  size_t off = ((size_t)(b * 16 + t) * Nn + n) * Aa + a;
  tok[(size_t)row * Aa + a] = f2bf(bf2f(ph[off]) + bf2f(delta[off]));
}

__global__ __launch_bounds__(256) void attn_core(
    const float* __restrict__ qkv, float* __restrict__ o) {
  constexpr int P = 580;
  __shared__ float sq[16 * P];
  __shared__ float ssc[4][16][17];
  int bk = blockIdx.x;
  int tid = threadIdx.x;
  const float* src = qkv + (size_t)bk * 16 * 576;
  for (int e = tid; e < 16 * 144; e += 256) {
    int r = e / 144, c4 = e % 144;
    float4 v = *(const float4*)(src + r * 576 + c4 * 4);
    *(float4*)(&sq[r * P + c4 * 4]) = v;
  }
  __syncthreads();
  int h = tid >> 6, lane = tid & 63;
#pragma unroll
  for (int s4 = 0; s4 < 4; ++s4) {
    int e = lane + 64 * s4;
    int i = e >> 4, j = e & 15;
    const float* q = sq + i * P + h * 48;
    const float* k2 = sq + j * P + 192 + h * 48;
    float s = 0.f;
#pragma unroll
    for (int d = 0; d < 48; ++d) s = fmaf(q[d], k2[d], s);
    ssc[h][i][j] = s * 0.14433756729740643f;  // 1/sqrt(48)
  }
  __syncthreads();
  if (lane < 16) {
    float* r = ssc[h][lane];
    float mx = r[0];
    for (int j = 1; j < 16; ++j) mx = fmaxf(mx, r[j]);
    float sum = 0.f;
    for (int j = 0; j < 16; ++j) {
      float ev = expf(r[j] - mx);
      r[j] = ev;
      sum += ev;
    }
    float inv = 1.0f / sum;
    for (int j = 0; j < 16; ++j) r[j] *= inv;
  }
  __syncthreads();
#pragma unroll
  for (int s4 = 0; s4 < 12; ++s4) {
    int e = lane + 64 * s4;
    int i = e / 48, d = e - i * 48;
    float s = 0.f;
#pragma unroll
    for (int j = 0; j < 16; ++j)
      s = fmaf(ssc[h][i][j], sq[j * P + 384 + h * 48 + d], s);
    o[((size_t)bk * 16 + i) * 192 + h * 48 + d] = s;
  }
}

__global__ void appart_kernel(const float* __restrict__ attout,
                              float* __restrict__ appart) {
  int bk = blockIdx.x;
  int a = threadIdx.x;
  float s = 0.f;
  for (int t = 0; t < Tt; ++t)
    s += attout[((size_t)bk * Tt + t) * Aa + a];
  appart[bk * Aa + a] = s;
}

// in-place fp32 LayerNorm over last dim (192); one wave per row
__global__ void ln32_kernel(float* __restrict__ buf,
                            const float* __restrict__ g,
                            const float* __restrict__ bb) {
  size_t row = (size_t)blockIdx.x * 4 + (threadIdx.x >> 6);
  int lane = threadIdx.x & 63;
  float* p = buf + row * Aa;
  float v0 = p[lane], v1 = p[lane + 64], v2 = p[lane + 128];
  float s = v0 + v1 + v2;
#pragma unroll
  for (int off = 32; off > 0; off >>= 1) s += __shfl_xor(s, off, 64);
  float m = s * (1.0f / 192.0f);
  float d0 = v0 - m, d1 = v1 - m, d2 = v2 - m;
  float ss = d0 * d0 + d1 * d1 + d2 * d2;
#pragma unroll
  for (int off = 32; off > 0; off >>= 1) ss += __shfl_xor(ss, off, 64);
  float inv = rsqrtf(ss * (1.0f / 192.0f) + 1e-5f);
  p[lane] = d0 * inv * g[lane] + bb[lane];
  p[lane + 64] = d1 * inv * g[lane + 64] + bb[lane + 64];
  p[lane + 128] = d2 * inv * g[lane + 128] + bb[lane + 128];
}

// depthwise 3x3 SAME conv over 14x14 + gelu; bf16 in/out
__global__ void conv2d_kernel(const ushortt* __restrict__ ph,
                              const float* __restrict__ ldw,
                              ushortt* __restrict__ og) {
  size_t e = (size_t)blockIdx.x * 256 + threadIdx.x;
  int a = (int)(e % Aa);
  size_t r = e / Aa;
  int n = (int)(r % Nn);
  int bt = (int)(r / Nn);
  int y = n / 14, x = n % 14;
  const ushortt* base = ph + (size_t)bt * Nn * Aa + a;
  const float* w = ldw + a * 9;
  float s = 0.f;
#pragma unroll
  for (int dy = -1; dy <= 1; ++dy) {
    int yy = y + dy;
    if (yy < 0 || yy >= 14) continue;
#pragma unroll
    for (int dx = -1; dx <= 1; ++dx) {
      int xc = x + dx;
      if (xc < 0 || xc >= 14) continue;
      s = fmaf(bf2f(base[(size_t)(yy * 14 + xc) * Aa]),
               w[(dy + 1) * 3 + (dx + 1)], s);
    }
  }
  og[e] = f2bf(gelu_f(s));
}

// depthwise k=3 SAME conv over t + gelu; bf16 in/out
__global__ void conv1d_kernel(const ushortt* __restrict__ delta,
                              const float* __restrict__ tdw,
                              ushortt* __restrict__ og) {
  size_t e = (size_t)blockIdx.x * 256 + threadIdx.x;
  int a = (int)(e % Aa);
  size_t r = e / Aa;
  int n = (int)(r % Nn);
  int bt = (int)(r / Nn);
  int t = bt & 15, b = bt >> 4;
  const float* w = tdw + a * 3;
  float s = 0.f;
#pragma unroll
  for (int j = 0; j < 3; ++j) {
    int tt = t + j - 1;
    if (tt >= 0 && tt < Tt)
      s = fmaf(bf2f(delta[((size_t)(b * Tt + tt) * Nn + n) * Aa + a]), w[j], s);
  }
  og[e] = f2bf(gelu_f(s));
}

// in-place LayerNorm over last dim (192); one wave per row (bf16)
__global__ void ln_kernel(ushortt* __restrict__ buf,
                          const float* __restrict__ g,
                          const float* __restrict__ bb) {
  size_t row = (size_t)blockIdx.x * 4 + (threadIdx.x >> 6);
  int lane = threadIdx.x & 63;
  ushortt* p = buf + row * Aa;
  float v0 = bf2f(p[lane]), v1 = bf2f(p[lane + 64]), v2 = bf2f(p[lane + 128]);
  float s = v0 + v1 + v2;
#pragma unroll
  for (int off = 32; off > 0; off >>= 1) s += __shfl_xor(s, off, 64);
  float m = s * (1.0f / 192.0f);
  float d0 = v0 - m, d1 = v1 - m, d2 = v2 - m;
  float ss = d0 * d0 + d1 * d1 + d2 * d2;
#pragma unroll
  for (int off = 32; off > 0; off >>= 1) ss += __shfl_xor(ss, off, 64);
  float inv = rsqrtf(ss * (1.0f / 192.0f) + 1e-5f);
  p[lane] = f2bf(d0 * inv * g[lane] + bb[lane]);
  p[lane + 64] = f2bf(d1 * inv * g[lane + 64] + bb[lane + 64]);
  p[lane + 128] = f2bf(d2 * inv * g[lane + 128] + bb[lane + 128]);
}

// posmap[bt*Nn + idx[bt,k]] = k+1 (posmap pre-zeroed)
__global__ void scatter_pos(const int* __restrict__ idx,
                            short* __restrict__ posmap) {
  int bt = blockIdx.x;
  int k = threadIdx.x;
  if (k < KK) posmap[bt * Nn + idx[bt * KK + k]] = (short)(k + 1);
}

// gate MLP + 3-way softmax; one block per b, 192 threads
__global__ void gate_kernel(const float* __restrict__ dppart,
                            const float* __restrict__ appart,
                            const float* __restrict__ w1,
                            const float* __restrict__ b1,
                            const float* __restrict__ w2,
                            const float* __restrict__ b2,
                            float* __restrict__ gw) {
  int b = blockIdx.x;
  __shared__ float sg[2 * Aa];
  __shared__ float sh[Aa];
  int tid = threadIdx.x;
  {
    float d = 0.f;
    for (int t2 = 0; t2 < Tt; ++t2) d += dppart[(b * Tt + t2) * Aa + tid];
    sg[tid] = d * (1.0f / 3136.0f);
    float a = 0.f;
    for (int k2 = 0; k2 < KK; ++k2) a += appart[(b * KK + k2) * Aa + tid];
    sg[Aa + tid] = a * (1.0f / 128.0f);
  }
  __syncthreads();
  {
    const float* w = w1 + (size_t)tid * 2 * Aa;
    float s = b1[tid];
#pragma unroll 8
    for (int j = 0; j < 2 * Aa; ++j) s = fmaf(sg[j], w[j], s);
    sh[tid] = gelu_f(s);
  }
  __syncthreads();
  float v[3];
#pragma unroll
  for (int i = 0; i < 3; ++i) {
    const float* w = w2 + (size_t)(i * Aa + tid) * Aa;
    float s = b2[i * Aa + tid];
#pragma unroll 8
    for (int j = 0; j < Aa; ++j) s = fmaf(sh[j], w[j], s);
    v[i] = s;
  }
  float mx = fmaxf(v[0], fmaxf(v[1], v[2]));
  float e0 = expf(v[0] - mx), e1 = expf(v[1] - mx), e2 = expf(v[2] - mx);
  float inv = 1.0f / (e0 + e1 + e2);
  gw[(b * 3 + 0) * Aa + tid] = e0 * inv;
  gw[(b * 3 + 1) * Aa + tid] = e1 * inv;
  gw[(b * 3 + 2) * Aa + tid] = e2 * inv;
}

// fused = gw0*local + gw1*trans + gw2*amap_ln; amap_ln from attln rows
// (anchors, via posmap) or anorm_b constant (non-anchors). fmean fp32.
__global__ void fused_kernel(const ushortt* __restrict__ local,
                             const ushortt* __restrict__ trans,
                             const float* __restrict__ attln,
                             const short* __restrict__ posmap,
                             const float* __restrict__ anb,
                             const float* __restrict__ gw,
                             ushortt* __restrict__ fused,
                             float* __restrict__ fmean) {
  int bt = blockIdx.x;
  int b = bt >> 4, t = bt & 15;
  int a = threadIdx.x;
  float g0 = gw[(b * 3 + 0) * Aa + a];
  float g1 = gw[(b * 3 + 1) * Aa + a];
  float g2 = gw[(b * 3 + 2) * Aa + a];
  float ab = anb[a];
  size_t base = (size_t)bt * Nn * Aa + a;
  float acc = 0.f;
  for (int n = 0; n < Nn; ++n) {
    size_t o = base + (size_t)n * Aa;
    short pos = posmap[bt * Nn + n];
    float am = pos ? attln[(((size_t)(b * KK + pos - 1) * Tt) + t) * Aa + a]
                   : ab;
    float f = g0 * bf2f(local[o]) + g1 * bf2f(trans[o]) + g2 * am;
    fused[o] = f2bf(f);
    acc += f;
  }
  fmean[bt * Aa + a] = acc;
}

// cls_out = cls_tok + (mean_n fused) @ cls_w.T + cls_b
__global__ void cls_kernel(const float* __restrict__ fmean,
                           const float* __restrict__ cw,
                           const float* __restrict__ cb,
                           const float* __restrict__ x,
                           float* __restrict__ out) {
  int bt = blockIdx.x;
  __shared__ float fm[Aa];
  int tid = threadIdx.x;
  if (tid < Aa) fm[tid] = fmean[bt * Aa + tid] * (1.0f / 196.0f);
  __syncthreads();
  for (int c = tid; c < Cc; c += 256) {
    const float* w = cw + (size_t)c * Aa;
    float s = cb[c];
#pragma unroll 8
    for (int a = 0; a < Aa; ++a) s = fmaf(fm[a], w[a], s);
    size_t off = (size_t)bt * (Nn + 1) * Cc + c;
    out[off] = x[off] + s;
  }
}

// ============================================================
extern "C" void kernel_launch(void* const* d_in, const int* in_sizes, int n_in,
                              void* d_out, int out_size, void* d_ws,
                              size_t ws_size, hipStream_t stream) {
  const float* x = (const float*)d_in[0];
  const float* down_w = (const float*)d_in[1];
  const float* down_b = (const float*)d_in[2];
  const float* ldw_w = (const float*)d_in[3];
  const float* lpw_w = (const float*)d_in[4];
  const float* lnorm_g = (const float*)d_in[5];
  const float* lnorm_b = (const float*)d_in[6];
  const float* tdw_w = (const float*)d_in[7];
  const float* tpw_w = (const float*)d_in[8];
  const float* tmlp_w1 = (const float*)d_in[9];
  const float* tmlp_b1 = (const float*)d_in[10];
  const float* tmlp_w2 = (const float*)d_in[11];
  const float* tmlp_b2 = (const float*)d_in[12];
  const float* tnorm_g = (const float*)d_in[13];
  const float* tnorm_b = (const float*)d_in[14];
  const float* attn_in_w = (const float*)d_in[15];
  const float* attn_in_b = (const float*)d_in[16];
  const float* attn_out_w = (const float*)d_in[17];
  const float* attn_out_b = (const float*)d_in[18];
  const float* aproj_w = (const float*)d_in[19];
  const float* aproj_b = (const float*)d_in[20];
  const float* anorm_g = (const float*)d_in[21];
  const float* anorm_b = (const float*)d_in[22];
  const float* gate_w1 = (const float*)d_in[23];
  const float* gate_b1 = (const float*)d_in[24];
  const float* gate_w2 = (const float*)d_in[25];
  const float* gate_b2 = (const float*)d_in[26];
  const float* up_w = (const float*)d_in[27];
  const float* up_b = (const float*)d_in[28];
  const float* cls_w = (const float*)d_in[29];
  const float* cls_b = (const float*)d_in[30];
  float* out = (float*)d_out;

  float* ws = (float*)d_ws;
  float* W0 = ws;              // ph bf16 -> trp bf16
  float* W1 = W0 + SZ;         // delta bf16 -> transition bf16
  float* W2 = W1 + SZ;         // attn scratch -> locg/trg/h1/fused bf16
  float* W3 = W2 + 2 * SZ;     // local bf16
  float* sal = W3 + SZ;
  float* attout = sal + BTN;
  float* dppart = attout + (size_t)BKT * Aa;
  float* appart = dppart + (size_t)BT * Aa;
  float* gw = appart + (size_t)Bb * KK * Aa;
  float* fmean = gw + (size_t)Bb * 3 * Aa;
  double* sal64 = (double*)(fmean + (size_t)BT * Aa);  // BT*NCAND doubles
  int* cand = (int*)(sal64 + (size_t)BT * NCAND);      // BT*NCAND ints
  int* idx = cand + (size_t)BT * NCAND;                // BT*KK ints
  float* wT = (float*)(idx + (size_t)BT * KK);         // Cc*Aa floats
  short* posmap = (short*)(wT + (size_t)Cc * Aa);      // BT*Nn shorts

  // bf16 views
  ushortt* ph_b    = (ushortt*)W0;
  ushortt* trp_b   = (ushortt*)W0;
  ushortt* delta_b = (ushortt*)W1;
  ushortt* trans_b = (ushortt*)W1;
  ushortt* locg_b  = (ushortt*)W2;
  ushortt* trg_b   = (ushortt*)W2;
  ushortt* h1_b    = (ushortt*)W2;
  ushortt* fused_b = (ushortt*)W2;
  ushortt* local_b = (ushortt*)W3;

  // attn-phase scratch inside W2 (dead until conv2d)
  ushortt* tok_b = (ushortt*)W2;                       // 2048*192 bf16
  float* qkvb  = W2 + (size_t)BKT * Aa / 2;            // 2048*576 f32
  float* obuf  = qkvb + (size_t)BKT * 3 * Aa;          // 2048*192 f32
  float* proj1 = obuf + (size_t)BKT * Aa;              // 2048*192 f32

  // 1. ph = patch @ down_w.T + down_b (bf16 out)
  gemm_mfma<float, ushortt, 1, 1, 0><<<dim3(2, 392), 256, 0, stream>>>(
      x, down_w, down_b, ph_b, nullptr, BTN, Aa, Cc);
  transpose_w<<<(Cc * Aa) / 256, 256, 0, stream>>>(down_w, wT);
  // 2. delta + dp partials
  delta_kernel<<<BT, Aa, 0, stream>>>(ph_b, delta_b, dppart);
  // 3. saliency: fp32 candidates -> f64 refine -> exact top-8
  sal_kernel<<<BTN / 4, 256, 0, stream>>>(delta_b, sal);
  topcand_kernel<<<BT, 64, 0, stream>>>(sal, cand);
  refine_kernel<<<dim3(BT, 2), 192, 0, stream>>>(x, wT, cand, sal64);
  select_kernel<<<BT, 64, 0, stream>>>(sal64, cand, idx);
  // 4. anchor attention
  gather_kernel<<<BKT, Aa, 0, stream>>>(ph_b, delta_b, idx, tok_b);
  gemm_mfma<ushortt, float, 0, 1, 0><<<dim3(6, 16), 256, 0, stream>>>(
      tok_b, attn_in_w, attn_in_b, qkvb, nullptr, BKT, 3 * Aa, Aa);
  attn_core<<<Bb * KK, 256, 0, stream>>>(qkvb, obuf);
  gemm_mfma<float, float, 0, 1, 0><<<dim3(2, 16), 256, 0, stream>>>(
      obuf, attn_out_w, attn_out_b, proj1, nullptr, BKT, Aa, Aa);
  gemm_mfma<float, float, 0, 1, 0><<<dim3(2, 16), 256, 0, stream>>>(
      proj1, aproj_w, aproj_b, attout, nullptr, BKT, Aa, Aa);
  appart_kernel<<<Bb * KK, Aa, 0, stream>>>(attout, appart);
  // 4b. LN the 2048 anchor rows in place (replaces full anchor-map LN)
  ln32_kernel<<<BKT / 4, 256, 0, stream>>>(attout, anorm_g, anorm_b);
  hipMemsetAsync(posmap, 0, (size_t)BT * Nn * sizeof(short), stream);
  scatter_pos<<<BT, 64, 0, stream>>>(idx, posmap);
  // 5. local branch
  conv2d_kernel<<<(unsigned)(SZ / 256), 256, 0, stream>>>(ph_b, ldw_w, locg_b);
  gemm_mfma<ushortt, ushortt, 0, 0, 0><<<dim3(2, 392), 256, 0, stream>>>(
      locg_b, lpw_w, nullptr, local_b, nullptr, BTN, Aa, Aa);
  ln_kernel<<<BTN / 4, 256, 0, stream>>>(local_b, lnorm_g, lnorm_b);
  // 6. transition branch
  conv1d_kernel<<<(unsigned)(SZ / 256), 256, 0, stream>>>(delta_b, tdw_w, trg_b);
  gemm_mfma<ushortt, ushortt, 0, 0, 0><<<dim3(2, 392), 256, 0, stream>>>(
      trg_b, tpw_w, nullptr, trp_b, nullptr, BTN, Aa, Aa);
  gemm_mfma<ushortt, ushortt, 0, 1, 1><<<dim3(4, 392), 256, 0, stream>>>(
      trp_b, tmlp_w1, tmlp_b1, h1_b, nullptr, BTN, 2 * Aa, Aa);
  gemm_mfma<ushortt, ushortt, 0, 1, 0><<<dim3(2, 392), 256, 0, stream>>>(
      h1_b, tmlp_w2, tmlp_b2, trans_b, nullptr, BTN, Aa, 2 * Aa);
  ln_kernel<<<BTN / 4, 256, 0, stream>>>(trans_b, tnorm_g, tnorm_b);
  // 8. gate
  gate_kernel<<<Bb, Aa, 0, stream>>>(dppart, appart, gate_w1, gate_b1,
                                     gate_w2, gate_b2, gw);
  // 9. fuse + output projections
  fused_kernel<<<BT, Aa, 0, stream>>>(local_b, trans_b, attout, posmap,
                                      anorm_b, gw, fused_b, fmean);
  gemm_mfma<ushortt, float, 0, 1, 2><<<dim3(8, 392), 256, 0, stream>>>(
      fused_b, up_w, up_b, out, x, BTN, Cc, Aa);
  cls_kernel<<<BT, 256, 0, stream>>>(fmean, cls_w, cls_b, x, out);
}

// Round 9
// 667.503 us; speedup vs baseline: 1.5266x; 1.0219x over previous
//
#include <hip/hip_runtime.h>
#include <math.h>

// ---- fixed problem dims ----
constexpr int Bb  = 16;
constexpr int Tt  = 16;
constexpr int Nn  = 196;   // patches (14x14)
constexpr int Cc  = 768;
constexpr int Aa  = 192;
constexpr int KK  = 8;     // TOPK
constexpr int NCAND = 16;  // fp32 candidates refined in f64
constexpr int BT  = Bb * Tt;            // 256
constexpr int BTN = BT * Nn;            // 50176
constexpr int BKT = Bb * KK * Tt;       // 2048 anchor-token rows
constexpr size_t SZ = (size_t)BTN * Aa; // 9,633,792 floats

typedef unsigned short ushortt;
typedef __attribute__((ext_vector_type(8))) short bf16x8;
typedef __attribute__((ext_vector_type(4))) float f32x4;
typedef __attribute__((ext_vector_type(4))) unsigned short u16x4;
typedef __attribute__((ext_vector_type(8))) unsigned short u16x8;

static __device__ __forceinline__ float gelu_f(float x) {
  return 0.5f * x * (1.0f + erff(x * 0.7071067811865476f));
}
static __device__ __forceinline__ ushortt f2bf(float f) {
  unsigned u = __float_as_uint(f);
  u += 0x7FFFu + ((u >> 16) & 1u);  // round-to-nearest-even
  return (ushortt)(u >> 16);
}
static __device__ __forceinline__ float bf2f(ushortt u) {
  return __uint_as_float(((unsigned)u) << 16);
}

// ============================================================
// bf16 MFMA GEMM: C[m,n] = sum_k A[m,k]*W[n,k] (+bias)(+epilogue)
// AT: float (staged->bf16) or ushort (bf16). CT: float or ushort.
// BM=64 BN=96 BK=32, 256 thr = 4 waves (2x2), wave tile 32x48
// (6 MFMA/step). Small BM => many blocks => occupancy (latency fix).
// LDS 25.6 KB => 6 blocks/CU. Single-pass LDS-staged coalesced epilogue.
// EPI: 0 plain, 1 gelu, 2 mapped residual fp32.
// Grid (Nc/96, M/64); col-fastest + bijective XCD swizzle (nwg%8==0).
// ============================================================
template <typename AT, typename CT, int ROWMAP, int BIAS, int EPI>
__global__ __launch_bounds__(256) void gemm_mfma(
    const AT* __restrict__ Ain, const float* __restrict__ W,
    const float* __restrict__ bias, CT* __restrict__ Cout,
    const float* __restrict__ resid, int M, int Nc, int K) {
  constexpr int PIT = 40;  // bf16 pitch (32+8 pad) -> worst 2-way (free)
  // staging: (2*64 + 2*96)*PIT*2B = 25600 B; epilogue reuses as 64x100 fp32
  __shared__ __align__(16) unsigned char smem[25600];
  ushortt (*As)[64 * PIT] = (ushortt(*)[64 * PIT])smem;
  ushortt (*Bs)[96 * PIT] = (ushortt(*)[96 * PIT])(smem + 2 * 64 * PIT * 2);
  const int tid = threadIdx.x;

  const int ncb = gridDim.x;
  const int nwg = ncb * gridDim.y;
  const int bid = blockIdx.y * ncb + blockIdx.x;
  const int cpx = nwg >> 3;
  const int swz = (bid & 7) * cpx + (bid >> 3);
  const int row0 = (swz / ncb) * 64;
  const int col0 = (swz % ncb) * 96;

  const int wid = tid >> 6;
  const int lane = tid & 63;
  const int wr = wid >> 1;       // 0..1 -> +32 rows
  const int wc = wid & 1;        // 0..1 -> +48 cols
  const int l15 = lane & 15;
  const int kgrp = lane >> 4;    // 0..3

  const int nsteps = K >> 5;

  const float* arowf[2];
  const ushortt* arowb[1];
  if constexpr (sizeof(AT) == 4) {
    const int srow = tid >> 3;   // 0..31
#pragma unroll
    for (int p = 0; p < 2; ++p) {
      int r = row0 + srow + 32 * p;
      if (ROWMAP) {
        int bt = r / Nn;
        int n = r - bt * Nn;
        arowf[p] = (const float*)Ain + (size_t)(bt * (Nn + 1) + 1 + n) * K;
      } else {
        arowf[p] = (const float*)Ain + (size_t)r * K;
      }
    }
  } else {
    const int srow2 = tid >> 2;  // 0..63
    arowb[0] = (const ushortt*)Ain + (size_t)(row0 + srow2) * K;
  }
  const float* browp[3];
  {
    const int srow = tid >> 3;
#pragma unroll
    for (int p = 0; p < 3; ++p)
      browp[p] = W + (size_t)(col0 + srow + 32 * p) * K;
  }

  f32x4 acc[2][3];
#pragma unroll
  for (int i = 0; i < 2; ++i)
#pragma unroll
    for (int j = 0; j < 3; ++j) acc[i][j] = (f32x4){0.f, 0.f, 0.f, 0.f};

  float4 apre[2], bpre[3];
  u16x8 apreb[1];

#define STAGE_LOAD(k0)                                                       \
  if constexpr (sizeof(AT) == 4) {                                           \
    const int quad = tid & 7;                                                \
    _Pragma("unroll") for (int p = 0; p < 2; ++p)                            \
        apre[p] = *(const float4*)(arowf[p] + (k0) + quad * 4);              \
  } else {                                                                   \
    const int quad2 = tid & 3;                                               \
    apreb[0] = *(const u16x8*)(arowb[0] + (k0) + quad2 * 8);                 \
  }                                                                          \
  {                                                                          \
    const int quad = tid & 7;                                                \
    _Pragma("unroll") for (int p = 0; p < 3; ++p)                            \
        bpre[p] = *(const float4*)(browp[p] + (k0) + quad * 4);              \
  }

#define STAGE_WRITE(buf)                                                     \
  if constexpr (sizeof(AT) == 4) {                                           \
    const int quad = tid & 7, srow = tid >> 3;                               \
    _Pragma("unroll") for (int p = 0; p < 2; ++p) {                          \
      u16x4 b = {f2bf(apre[p].x), f2bf(apre[p].y), f2bf(apre[p].z),          \
                 f2bf(apre[p].w)};                                           \
      *(u16x4*)&As[buf][(srow + 32 * p) * PIT + quad * 4] = b;               \
    }                                                                        \
  } else {                                                                   \
    const int quad2 = tid & 3, srow2 = tid >> 2;                             \
    *(u16x8*)&As[buf][srow2 * PIT + quad2 * 8] = apreb[0];                   \
  }                                                                          \
  {                                                                          \
    const int quad = tid & 7, srow = tid >> 3;                               \
    _Pragma("unroll") for (int p = 0; p < 3; ++p) {                          \
      u16x4 b = {f2bf(bpre[p].x), f2bf(bpre[p].y), f2bf(bpre[p].z),          \
                 f2bf(bpre[p].w)};                                           \
      *(u16x4*)&Bs[buf][(srow + 32 * p) * PIT + quad * 4] = b;               \
    }                                                                        \
  }

  STAGE_LOAD(0);
  STAGE_WRITE(0);
  __syncthreads();

  int cur = 0;
  for (int step = 0; step < nsteps; ++step) {
    const bool pref = (step + 1 < nsteps);
    if (pref) {
      int k0 = (step + 1) << 5;
      STAGE_LOAD(k0);
    }
    bf16x8 af[2], bfv[3];
#pragma unroll
    for (int fm = 0; fm < 2; ++fm)
      af[fm] = *(const bf16x8*)&As[cur][(wr * 32 + fm * 16 + l15) * PIT + kgrp * 8];
#pragma unroll
    for (int fn = 0; fn < 3; ++fn)
      bfv[fn] = *(const bf16x8*)&Bs[cur][(wc * 48 + fn * 16 + l15) * PIT + kgrp * 8];
#pragma unroll
    for (int fm = 0; fm < 2; ++fm)
#pragma unroll
      for (int fn = 0; fn < 3; ++fn)
        acc[fm][fn] = __builtin_amdgcn_mfma_f32_16x16x32_bf16(
            af[fm], bfv[fn], acc[fm][fn], 0, 0, 0);
    if (pref) {
      STAGE_WRITE(cur ^ 1);
    }
    __syncthreads();
    cur ^= 1;
  }
#undef STAGE_LOAD
#undef STAGE_WRITE

  // ---- single-pass LDS-staged epilogue: coalesced global stores ----
  constexpr int EP = 100;  // fp32 pitch for 96 cols (+4 pad)
  float* epi = (float*)smem;  // 64*100*4 = 25600 B
#pragma unroll
  for (int fm = 0; fm < 2; ++fm) {
    int rl = wr * 32 + fm * 16 + kgrp * 4;
#pragma unroll
    for (int fn = 0; fn < 3; ++fn) {
      int cl = wc * 48 + fn * 16 + l15;
#pragma unroll
      for (int j = 0; j < 4; ++j)
        epi[(rl + j) * EP + cl] = acc[fm][fn][j];
    }
  }
  __syncthreads();
#pragma unroll
  for (int it = 0; it < 6; ++it) {
    int f = it * 256 + tid;        // 0..1535 over 64 rows x 24 float4
    int r = f / 24, c4 = f - r * 24;
    float4 v = *(const float4*)&epi[r * EP + c4 * 4];
    int c = col0 + c4 * 4;
    if (BIAS) {
      float4 bv = *(const float4*)(bias + c);
      v.x += bv.x; v.y += bv.y; v.z += bv.z; v.w += bv.w;
    }
    if (EPI == 1) {
      v.x = gelu_f(v.x); v.y = gelu_f(v.y);
      v.z = gelu_f(v.z); v.w = gelu_f(v.w);
    }
    int R = row0 + r;
    if constexpr (EPI == 2) {
      int bt2 = R / Nn, n2 = R - bt2 * Nn;
      size_t off = (size_t)(bt2 * (Nn + 1) + 1 + n2) * Nc + c;
      float4 rv = *(const float4*)(resid + off);
      v.x += rv.x; v.y += rv.y; v.z += rv.z; v.w += rv.w;
      *(float4*)((float*)Cout + off) = v;
    } else if constexpr (sizeof(CT) == 4) {
      *(float4*)((float*)Cout + (size_t)R * Nc + c) = v;
    } else {
      u16x4 ob = {f2bf(v.x), f2bf(v.y), f2bf(v.z), f2bf(v.w)};
      *(u16x4*)((ushortt*)Cout + (size_t)R * Nc + c) = ob;
    }
  }
}

// ============================================================
// delta (bf16) + per-(b,t) |delta| partials
// ============================================================
__global__ void delta_kernel(const ushortt* __restrict__ ph,
                             ushortt* __restrict__ delta,
                             float* __restrict__ dppart) {
  int bt = blockIdx.x;
  int t = bt & 15;
  int a = threadIdx.x;
  const ushortt* cur = ph + (size_t)bt * Nn * Aa + a;
  ushortt* dl = delta + (size_t)bt * Nn * Aa + a;
  float acc = 0.f;
  if (t == 0) {
    for (int n = 0; n < Nn; ++n) dl[(size_t)n * Aa] = 0;
  } else {
    const ushortt* prev = cur - (size_t)Nn * Aa;
    for (int n = 0; n < Nn; ++n) {
      float d = bf2f(cur[(size_t)n * Aa]) - bf2f(prev[(size_t)n * Aa]);
      dl[(size_t)n * Aa] = f2bf(d);
      acc += fabsf(d);
    }
  }
  dppart[bt * Aa + a] = acc;
}

// sal[row] = mean_a |delta[row,a]| (fp32, candidate stage only)
__global__ void sal_kernel(const ushortt* __restrict__ delta,
                           float* __restrict__ sal) {
  int row = blockIdx.x * 4 + (threadIdx.x >> 6);
  int lane = threadIdx.x & 63;
  const ushortt* d = delta + (size_t)row * Aa;
  float s = fabsf(bf2f(d[lane])) + fabsf(bf2f(d[lane + 64])) +
            fabsf(bf2f(d[lane + 128]));
#pragma unroll
  for (int off = 32; off > 0; off >>= 1) s += __shfl_xor(s, off, 64);
  if (lane == 0) sal[row] = s * (1.0f / 192.0f);
}

// ============================================================
// top-16 fp32 candidates per (b,t); descending val, ties -> smaller n
// ============================================================
__global__ void topcand_kernel(const float* __restrict__ sal,
                               int* __restrict__ cand) {
  int bt = blockIdx.x;
  int lane = threadIdx.x;
  unsigned long long key[4];
#pragma unroll
  for (int j = 0; j < 4; ++j) {
    int n = lane + 64 * j;
    if (n < Nn) {
      unsigned fb = __float_as_uint(sal[(size_t)bt * Nn + n]);
      key[j] = ((unsigned long long)fb << 32) |
               (unsigned long long)(0xFFFFFFFFu - (unsigned)n);
    } else {
      key[j] = 0ULL;
    }
  }
  for (int r = 0; r < NCAND; ++r) {
    unsigned long long m = key[0];
    if (key[1] > m) m = key[1];
    if (key[2] > m) m = key[2];
    if (key[3] > m) m = key[3];
#pragma unroll
    for (int off = 32; off > 0; off >>= 1) {
      unsigned long long o = __shfl_xor(m, off, 64);
      if (o > m) m = o;
    }
    if (lane == 0)
      cand[bt * NCAND + r] = (int)(0xFFFFFFFFu - (unsigned)(m & 0xFFFFFFFFull));
#pragma unroll
    for (int j = 0; j < 4; ++j)
      if (key[j] == m) key[j] = 0ULL;
  }
}

// one-time transpose: wT[c][a] = down_w[a][c]
__global__ void transpose_w(const float* __restrict__ w,
                            float* __restrict__ wT) {
  int e = blockIdx.x * 256 + threadIdx.x;  // over Cc*Aa
  int c = e / Aa, a = e - c * Aa;
  wT[e] = w[(size_t)a * Cc + c];
}

// ============================================================
// f64 refine, 8 candidates per block (grid BT x 2, 192 thr).
// diff staged once in LDS (f64); w read COALESCED via wT[c][a].
// ============================================================
__global__ __launch_bounds__(192) void refine_kernel(
    const float* __restrict__ x, const float* __restrict__ wT,
    const int* __restrict__ cand, double* __restrict__ sal64) {
  int bt = blockIdx.x;
  int grp = blockIdx.y;
  int t = bt & 15;
  int a = threadIdx.x;
  if (t == 0) {
    if (a < 8) sal64[bt * NCAND + grp * 8 + a] = 0.0;
    return;
  }
  __shared__ double sdiff[8][Cc];  // 49 KB
  const float* xt = x + ((size_t)bt * (Nn + 1) + 1) * Cc;
  const float* xp = xt - (size_t)(Nn + 1) * Cc;
  for (int g = 0; g < 8; ++g) {
    int n = cand[bt * NCAND + grp * 8 + g];
    const float* rt = xt + (size_t)n * Cc;
    const float* rp = xp + (size_t)n * Cc;
    for (int c = a; c < Cc; c += 192)
      sdiff[g][c] = (double)rt[c] - (double)rp[c];
  }
  __syncthreads();
  double acc[8] = {};
  for (int c = 0; c < Cc; ++c) {
    double wv = (double)wT[(size_t)c * Aa + a];  // coalesced across lanes
#pragma unroll
    for (int g = 0; g < 8; ++g) acc[g] = fma(wv, sdiff[g][c], acc[g]);
  }
  __shared__ double part[3][8];
  int wvx = a >> 6, ln = a & 63;
#pragma unroll
  for (int g = 0; g < 8; ++g) {
    double v = fabs(acc[g]);
#pragma unroll
    for (int off = 32; off > 0; off >>= 1) v += __shfl_xor(v, off, 64);
    if (ln == 0) part[wvx][g] = v;
  }
  __syncthreads();
  if (a < 8) {
    double s = part[0][a] + part[1][a] + part[2][a];
    sal64[bt * NCAND + grp * 8 + a] = s * (1.0 / 192.0);
  }
}

// final top-8 by (sal64 desc, n asc)
__global__ void select_kernel(const double* __restrict__ sal64,
                              const int* __restrict__ cand,
                              int* __restrict__ idx) {
  int bt = blockIdx.x;
  int t = bt & 15;
  if (threadIdx.x != 0) return;
  if (t == 0) {
    for (int r = 0; r < KK; ++r) idx[bt * KK + r] = r;
    return;
  }
  double v[NCAND];
  int nn[NCAND];
  bool used[NCAND];
  for (int i = 0; i < NCAND; ++i) {
    v[i] = sal64[bt * NCAND + i];
    nn[i] = cand[bt * NCAND + i];
    used[i] = false;
  }
  for (int r = 0; r < KK; ++r) {
    int best = -1;
    for (int i = 0; i < NCAND; ++i) {
      if (used[i]) continue;
      if (best < 0 || v[i] > v[best] ||
          (v[i] == v[best] && nn[i] < nn[best]))
        best = i;
    }
    used[best] = true;
    idx[bt * KK + r] = nn[best];
  }
}

// ============================================================
// anchor attention: gather(bf16) -> GEMM qkv -> core -> GEMMs
// ============================================================
__global__ void gather_kernel(const ushortt* __restrict__ ph,
                              const ushortt* __restrict__ delta,
                              const int* __restrict__ idx,
                              ushortt* __restrict__ tok) {
  int row = blockIdx.x;  // (b*KK+k)*16+t
  int t = row & 15;
  int bk = row >> 4;
  int b = bk >> 3, k = bk & 7;
  int a = threadIdx.x;
  int n = idx[(b * 16 + t) * KK + k];
  size_t off = ((size_t)(b * 16 + t) * Nn + n) * Aa + a;
  tok[(size_t)row * Aa + a] = f2bf(bf2f(ph[off]) + bf2f(delta[off]));
}

__global__ __launch_bounds__(256) void attn_core(
    const float* __restrict__ qkv, float* __restrict__ o) {
  constexpr int P = 580;
  __shared__ float sq[16 * P];
  __shared__ float ssc[4][16][17];
  int bk = blockIdx.x;
  int tid = threadIdx.x;
  const float* src = qkv + (size_t)bk * 16 * 576;
  for (int e = tid; e < 16 * 144; e += 256) {
    int r = e / 144, c4 = e % 144;
    float4 v = *(const float4*)(src + r * 576 + c4 * 4);
    *(float4*)(&sq[r * P + c4 * 4]) = v;
  }
  __syncthreads();
  int h = tid >> 6, lane = tid & 63;
#pragma unroll
  for (int s4 = 0; s4 < 4; ++s4) {
    int e = lane + 64 * s4;
    int i = e >> 4, j = e & 15;
    const float* q = sq + i * P + h * 48;
    const float* k2 = sq + j * P + 192 + h * 48;
    float s = 0.f;
#pragma unroll
    for (int d = 0; d < 48; ++d) s = fmaf(q[d], k2[d], s);
    ssc[h][i][j] = s * 0.14433756729740643f;  // 1/sqrt(48)
  }
  __syncthreads();
  if (lane < 16) {
    float* r = ssc[h][lane];
    float mx = r[0];
    for (int j = 1; j < 16; ++j) mx = fmaxf(mx, r[j]);
    float sum = 0.f;
    for (int j = 0; j < 16; ++j) {
      float ev = expf(r[j] - mx);
      r[j] = ev;
      sum += ev;
    }
    float inv = 1.0f / sum;
    for (int j = 0; j < 16; ++j) r[j] *= inv;
  }
  __syncthreads();
#pragma unroll
  for (int s4 = 0; s4 < 12; ++s4) {
    int e = lane + 64 * s4;
    int i = e / 48, d = e - i * 48;
    float s = 0.f;
#pragma unroll
    for (int j = 0; j < 16; ++j)
      s = fmaf(ssc[h][i][j], sq[j * P + 384 + h * 48 + d], s);
    o[((size_t)bk * 16 + i) * 192 + h * 48 + d] = s;
  }
}

__global__ void appart_kernel(const float* __restrict__ attout,
                              float* __restrict__ appart) {
  int bk = blockIdx.x;
  int a = threadIdx.x;
  float s = 0.f;
  for (int t = 0; t < Tt; ++t)
    s += attout[((size_t)bk * Tt + t) * Aa + a];
  appart[bk * Aa + a] = s;
}

// in-place fp32 LayerNorm over last dim (192); one wave per row
__global__ void ln32_kernel(float* __restrict__ buf,
                            const float* __restrict__ g,
                            const float* __restrict__ bb) {
  size_t row = (size_t)blockIdx.x * 4 + (threadIdx.x >> 6);
  int lane = threadIdx.x & 63;
  float* p = buf + row * Aa;
  float v0 = p[lane], v1 = p[lane + 64], v2 = p[lane + 128];
  float s = v0 + v1 + v2;
#pragma unroll
  for (int off = 32; off > 0; off >>= 1) s += __shfl_xor(s, off, 64);
  float m = s * (1.0f / 192.0f);
  float d0 = v0 - m, d1 = v1 - m, d2 = v2 - m;
  float ss = d0 * d0 + d1 * d1 + d2 * d2;
#pragma unroll
  for (int off = 32; off > 0; off >>= 1) ss += __shfl_xor(ss, off, 64);
  float inv = rsqrtf(ss * (1.0f / 192.0f) + 1e-5f);
  p[lane] = d0 * inv * g[lane] + bb[lane];
  p[lane + 64] = d1 * inv * g[lane + 64] + bb[lane + 64];
  p[lane + 128] = d2 * inv * g[lane + 128] + bb[lane + 128];
}

// depthwise 3x3 SAME conv over 14x14 + gelu; bf16 in/out
__global__ void conv2d_kernel(const ushortt* __restrict__ ph,
                              const float* __restrict__ ldw,
                              ushortt* __restrict__ og) {
  size_t e = (size_t)blockIdx.x * 256 + threadIdx.x;
  int a = (int)(e % Aa);
  size_t r = e / Aa;
  int n = (int)(r % Nn);
  int bt = (int)(r / Nn);
  int y = n / 14, x = n % 14;
  const ushortt* base = ph + (size_t)bt * Nn * Aa + a;
  const float* w = ldw + a * 9;
  float s = 0.f;
#pragma unroll
  for (int dy = -1; dy <= 1; ++dy) {
    int yy = y + dy;
    if (yy < 0 || yy >= 14) continue;
#pragma unroll
    for (int dx = -1; dx <= 1; ++dx) {
      int xc = x + dx;
      if (xc < 0 || xc >= 14) continue;
      s = fmaf(bf2f(base[(size_t)(yy * 14 + xc) * Aa]),
               w[(dy + 1) * 3 + (dx + 1)], s);
    }
  }
  og[e] = f2bf(gelu_f(s));
}

// depthwise k=3 SAME conv over t + gelu; bf16 in/out
__global__ void conv1d_kernel(const ushortt* __restrict__ delta,
                              const float* __restrict__ tdw,
                              ushortt* __restrict__ og) {
  size_t e = (size_t)blockIdx.x * 256 + threadIdx.x;
  int a = (int)(e % Aa);
  size_t r = e / Aa;
  int n = (int)(r % Nn);
  int bt = (int)(r / Nn);
  int t = bt & 15, b = bt >> 4;
  const float* w = tdw + a * 3;
  float s = 0.f;
#pragma unroll
  for (int j = 0; j < 3; ++j) {
    int tt = t + j - 1;
    if (tt >= 0 && tt < Tt)
      s = fmaf(bf2f(delta[((size_t)(b * Tt + tt) * Nn + n) * Aa + a]), w[j], s);
  }
  og[e] = f2bf(gelu_f(s));
}

// in-place LayerNorm over last dim (192); one wave per row (bf16)
__global__ void ln_kernel(ushortt* __restrict__ buf,
                          const float* __restrict__ g,
                          const float* __restrict__ bb) {
  size_t row = (size_t)blockIdx.x * 4 + (threadIdx.x >> 6);
  int lane = threadIdx.x & 63;
  ushortt* p = buf + row * Aa;
  float v0 = bf2f(p[lane]), v1 = bf2f(p[lane + 64]), v2 = bf2f(p[lane + 128]);
  float s = v0 + v1 + v2;
#pragma unroll
  for (int off = 32; off > 0; off >>= 1) s += __shfl_xor(s, off, 64);
  float m = s * (1.0f / 192.0f);
  float d0 = v0 - m, d1 = v1 - m, d2 = v2 - m;
  float ss = d0 * d0 + d1 * d1 + d2 * d2;
#pragma unroll
  for (int off = 32; off > 0; off >>= 1) ss += __shfl_xor(ss, off, 64);
  float inv = rsqrtf(ss * (1.0f / 192.0f) + 1e-5f);
  p[lane] = f2bf(d0 * inv * g[lane] + bb[lane]);
  p[lane + 64] = f2bf(d1 * inv * g[lane + 64] + bb[lane + 64]);
  p[lane + 128] = f2bf(d2 * inv * g[lane + 128] + bb[lane + 128]);
}

// posmap[bt*Nn + idx[bt,k]] = k+1 (posmap pre-zeroed)
__global__ void scatter_pos(const int* __restrict__ idx,
                            short* __restrict__ posmap) {
  int bt = blockIdx.x;
  int k = threadIdx.x;
  if (k < KK) posmap[bt * Nn + idx[bt * KK + k]] = (short)(k + 1);
}

// gate MLP + 3-way softmax; one block per b, 192 threads
__global__ void gate_kernel(const float* __restrict__ dppart,
                            const float* __restrict__ appart,
                            const float* __restrict__ w1,
                            const float* __restrict__ b1,
                            const float* __restrict__ w2,
                            const float* __restrict__ b2,
                            float* __restrict__ gw) {
  int b = blockIdx.x;
  __shared__ float sg[2 * Aa];
  __shared__ float sh[Aa];
  int tid = threadIdx.x;
  {
    float d = 0.f;
    for (int t2 = 0; t2 < Tt; ++t2) d += dppart[(b * Tt + t2) * Aa + tid];
    sg[tid] = d * (1.0f / 3136.0f);
    float a = 0.f;
    for (int k2 = 0; k2 < KK; ++k2) a += appart[(b * KK + k2) * Aa + tid];
    sg[Aa + tid] = a * (1.0f / 128.0f);
  }
  __syncthreads();
  {
    const float* w = w1 + (size_t)tid * 2 * Aa;
    float s = b1[tid];
#pragma unroll 8
    for (int j = 0; j < 2 * Aa; ++j) s = fmaf(sg[j], w[j], s);
    sh[tid] = gelu_f(s);
  }
  __syncthreads();
  float v[3];
#pragma unroll
  for (int i = 0; i < 3; ++i) {
    const float* w = w2 + (size_t)(i * Aa + tid) * Aa;
    float s = b2[i * Aa + tid];
#pragma unroll 8
    for (int j = 0; j < Aa; ++j) s = fmaf(sh[j], w[j], s);
    v[i] = s;
  }
  float mx = fmaxf(v[0], fmaxf(v[1], v[2]));
  float e0 = expf(v[0] - mx), e1 = expf(v[1] - mx), e2 = expf(v[2] - mx);
  float inv = 1.0f / (e0 + e1 + e2);
  gw[(b * 3 + 0) * Aa + tid] = e0 * inv;
  gw[(b * 3 + 1) * Aa + tid] = e1 * inv;
  gw[(b * 3 + 2) * Aa + tid] = e2 * inv;
}

// fused = gw0*local + gw1*trans + gw2*amap_ln; amap_ln from attln rows
// (anchors, via posmap) or anorm_b constant (non-anchors). fmean fp32.
__global__ void fused_kernel(const ushortt* __restrict__ local,
                             const ushortt* __restrict__ trans,
                             const float* __restrict__ attln,
                             const short* __restrict__ posmap,
                             const float* __restrict__ anb,
                             const float* __restrict__ gw,
                             ushortt* __restrict__ fused,
                             float* __restrict__ fmean) {
  int bt = blockIdx.x;
  int b = bt >> 4, t = bt & 15;
  int a = threadIdx.x;
  float g0 = gw[(b * 3 + 0) * Aa + a];
  float g1 = gw[(b * 3 + 1) * Aa + a];
  float g2 = gw[(b * 3 + 2) * Aa + a];
  float ab = anb[a];
  size_t base = (size_t)bt * Nn * Aa + a;
  float acc = 0.f;
  for (int n = 0; n < Nn; ++n) {
    size_t o = base + (size_t)n * Aa;
    short pos = posmap[bt * Nn + n];
    float am = pos ? attln[(((size_t)(b * KK + pos - 1) * Tt) + t) * Aa + a]
                   : ab;
    float f = g0 * bf2f(local[o]) + g1 * bf2f(trans[o]) + g2 * am;
    fused[o] = f2bf(f);
    acc += f;
  }
  fmean[bt * Aa + a] = acc;
}

// cls_out = cls_tok + (mean_n fused) @ cls_w.T + cls_b
__global__ void cls_kernel(const float* __restrict__ fmean,
                           const float* __restrict__ cw,
                           const float* __restrict__ cb,
                           const float* __restrict__ x,
                           float* __restrict__ out) {
  int bt = blockIdx.x;
  __shared__ float fm[Aa];
  int tid = threadIdx.x;
  if (tid < Aa) fm[tid] = fmean[bt * Aa + tid] * (1.0f / 196.0f);
  __syncthreads();
  for (int c = tid; c < Cc; c += 256) {
    const float* w = cw + (size_t)c * Aa;
    float s = cb[c];
#pragma unroll 8
    for (int a = 0; a < Aa; ++a) s = fmaf(fm[a], w[a], s);
    size_t off = (size_t)bt * (Nn + 1) * Cc + c;
    out[off] = x[off] + s;
  }
}

// ============================================================
extern "C" void kernel_launch(void* const* d_in, const int* in_sizes, int n_in,
                              void* d_out, int out_size, void* d_ws,
                              size_t ws_size, hipStream_t stream) {
  const float* x = (const float*)d_in[0];
  const float* down_w = (const float*)d_in[1];
  const float* down_b = (const float*)d_in[2];
  const float* ldw_w = (const float*)d_in[3];
  const float* lpw_w = (const float*)d_in[4];
  const float* lnorm_g = (const float*)d_in[5];
  const float* lnorm_b = (const float*)d_in[6];
  const float* tdw_w = (const float*)d_in[7];
  const float* tpw_w = (const float*)d_in[8];
  const float* tmlp_w1 = (const float*)d_in[9];
  const float* tmlp_b1 = (const float*)d_in[10];
  const float* tmlp_w2 = (const float*)d_in[11];
  const float* tmlp_b2 = (const float*)d_in[12];
  const float* tnorm_g = (const float*)d_in[13];
  const float* tnorm_b = (const float*)d_in[14];
  const float* attn_in_w = (const float*)d_in[15];
  const float* attn_in_b = (const float*)d_in[16];
  const float* attn_out_w = (const float*)d_in[17];
  const float* attn_out_b = (const float*)d_in[18];
  const float* aproj_w = (const float*)d_in[19];
  const float* aproj_b = (const float*)d_in[20];
  const float* anorm_g = (const float*)d_in[21];
  const float* anorm_b = (const float*)d_in[22];
  const float* gate_w1 = (const float*)d_in[23];
  const float* gate_b1 = (const float*)d_in[24];
  const float* gate_w2 = (const float*)d_in[25];
  const float* gate_b2 = (const float*)d_in[26];
  const float* up_w = (const float*)d_in[27];
  const float* up_b = (const float*)d_in[28];
  const float* cls_w = (const float*)d_in[29];
  const float* cls_b = (const float*)d_in[30];
  float* out = (float*)d_out;

  float* ws = (float*)d_ws;
  float* W0 = ws;              // ph bf16 -> trp bf16
  float* W1 = W0 + SZ;         // delta bf16 -> transition bf16
  float* W2 = W1 + SZ;         // attn scratch -> locg/trg/h1/fused bf16
  float* W3 = W2 + 2 * SZ;     // local bf16
  float* sal = W3 + SZ;
  float* attout = sal + BTN;
  float* dppart = attout + (size_t)BKT * Aa;
  float* appart = dppart + (size_t)BT * Aa;
  float* gw = appart + (size_t)Bb * KK * Aa;
  float* fmean = gw + (size_t)Bb * 3 * Aa;
  double* sal64 = (double*)(fmean + (size_t)BT * Aa);  // BT*NCAND doubles
  int* cand = (int*)(sal64 + (size_t)BT * NCAND);      // BT*NCAND ints
  int* idx = cand + (size_t)BT * NCAND;                // BT*KK ints
  float* wT = (float*)(idx + (size_t)BT * KK);         // Cc*Aa floats
  short* posmap = (short*)(wT + (size_t)Cc * Aa);      // BT*Nn shorts

  // bf16 views
  ushortt* ph_b    = (ushortt*)W0;
  ushortt* trp_b   = (ushortt*)W0;
  ushortt* delta_b = (ushortt*)W1;
  ushortt* trans_b = (ushortt*)W1;
  ushortt* locg_b  = (ushortt*)W2;
  ushortt* trg_b   = (ushortt*)W2;
  ushortt* h1_b    = (ushortt*)W2;
  ushortt* fused_b = (ushortt*)W2;
  ushortt* local_b = (ushortt*)W3;

  // attn-phase scratch inside W2 (dead until conv2d)
  ushortt* tok_b = (ushortt*)W2;                       // 2048*192 bf16
  float* qkvb  = W2 + (size_t)BKT * Aa / 2;            // 2048*576 f32
  float* obuf  = qkvb + (size_t)BKT * 3 * Aa;          // 2048*192 f32
  float* proj1 = obuf + (size_t)BKT * Aa;              // 2048*192 f32

  // 1. ph = patch @ down_w.T + down_b (bf16 out)
  gemm_mfma<float, ushortt, 1, 1, 0><<<dim3(2, 784), 256, 0, stream>>>(
      x, down_w, down_b, ph_b, nullptr, BTN, Aa, Cc);
  transpose_w<<<(Cc * Aa) / 256, 256, 0, stream>>>(down_w, wT);
  // 2. delta + dp partials
  delta_kernel<<<BT, Aa, 0, stream>>>(ph_b, delta_b, dppart);
  // 3. saliency: fp32 candidates -> f64 refine -> exact top-8
  sal_kernel<<<BTN / 4, 256, 0, stream>>>(delta_b, sal);
  topcand_kernel<<<BT, 64, 0, stream>>>(sal, cand);
  refine_kernel<<<dim3(BT, 2), 192, 0, stream>>>(x, wT, cand, sal64);
  select_kernel<<<BT, 64, 0, stream>>>(sal64, cand, idx);
  // 4. anchor attention
  gather_kernel<<<BKT, Aa, 0, stream>>>(ph_b, delta_b, idx, tok_b);
  gemm_mfma<ushortt, float, 0, 1, 0><<<dim3(6, 32), 256, 0, stream>>>(
      tok_b, attn_in_w, attn_in_b, qkvb, nullptr, BKT, 3 * Aa, Aa);
  attn_core<<<Bb * KK, 256, 0, stream>>>(qkvb, obuf);
  gemm_mfma<float, float, 0, 1, 0><<<dim3(2, 32), 256, 0, stream>>>(
      obuf, attn_out_w, attn_out_b, proj1, nullptr, BKT, Aa, Aa);
  gemm_mfma<float, float, 0, 1, 0><<<dim3(2, 32), 256, 0, stream>>>(
      proj1, aproj_w, aproj_b, attout, nullptr, BKT, Aa, Aa);
  appart_kernel<<<Bb * KK, Aa, 0, stream>>>(attout, appart);
  // 4b. LN the 2048 anchor rows in place (replaces full anchor-map LN)
  ln32_kernel<<<BKT / 4, 256, 0, stream>>>(attout, anorm_g, anorm_b);
  hipMemsetAsync(posmap, 0, (size_t)BT * Nn * sizeof(short), stream);
  scatter_pos<<<BT, 64, 0, stream>>>(idx, posmap);
  // 5. local branch
  conv2d_kernel<<<(unsigned)(SZ / 256), 256, 0, stream>>>(ph_b, ldw_w, locg_b);
  gemm_mfma<ushortt, ushortt, 0, 0, 0><<<dim3(2, 784), 256, 0, stream>>>(
      locg_b, lpw_w, nullptr, local_b, nullptr, BTN, Aa, Aa);
  ln_kernel<<<BTN / 4, 256, 0, stream>>>(local_b, lnorm_g, lnorm_b);
  // 6. transition branch
  conv1d_kernel<<<(unsigned)(SZ / 256), 256, 0, stream>>>(delta_b, tdw_w, trg_b);
  gemm_mfma<ushortt, ushortt, 0, 0, 0><<<dim3(2, 784), 256, 0, stream>>>(
      trg_b, tpw_w, nullptr, trp_b, nullptr, BTN, Aa, Aa);
  gemm_mfma<ushortt, ushortt, 0, 1, 1><<<dim3(4, 784), 256, 0, stream>>>(
      trp_b, tmlp_w1, tmlp_b1, h1_b, nullptr, BTN, 2 * Aa, Aa);
  gemm_mfma<ushortt, ushortt, 0, 1, 0><<<dim3(2, 784), 256, 0, stream>>>(
      h1_b, tmlp_w2, tmlp_b2, trans_b, nullptr, BTN, Aa, 2 * Aa);
  ln_kernel<<<BTN / 4, 256, 0, stream>>>(trans_b, tnorm_g, tnorm_b);
  // 8. gate
  gate_kernel<<<Bb, Aa, 0, stream>>>(dppart, appart, gate_w1, gate_b1,
                                     gate_w2, gate_b2, gw);
  // 9. fuse + output projections
  fused_kernel<<<BT, Aa, 0, stream>>>(local_b, trans_b, attout, posmap,
                                      anorm_b, gw, fused_b, fmean);
  gemm_mfma<ushortt, float, 0, 1, 2><<<dim3(8, 784), 256, 0, stream>>>(
      fused_b, up_w, up_b, out, x, BTN, Cc, Aa);
  cls_kernel<<<BT, 256, 0, stream>>>(fmean, cls_w, cls_b, x, out);
}